// Round 2
// baseline (5121.575 us; speedup 1.0000x reference)
//
#include <hip/hip_runtime.h>
#include <hip/hip_bf16.h>
#include <math.h>

// ---------------------------------------------------------------------------
// Mamba forward, fp32 baseline (workspace-slim: fits 192 MiB of d_ws).
// Shapes: B=2, L=4096, D_MODEL=1024, D_INNER=2048, E2=4096, D_STATE=8,
//         D_CONV=4, DT_RANK=64, NK=80 (=64+8+8), R_RANK=8.
//
// Buffers:
//   d_ws : xz (B*L,4096) fp32   [x = cols 0..2047 (becomes y after scan),
//                                z = cols 2048..4095]
//          xt (B*L,2048) fp32   (post-conv silu'd == u)
//   d_out: first 672K floats used as scratch for x_dbl (B*L,80) + A_eff
//          (2048,8) until the final GEMM overwrites d_out entirely.
// Kernel order: in_proj GEMM -> a_eff -> conv+silu -> x_proj GEMM ->
//               scan (fused dt-GEMM + softplus + gating, writes y over xz.x)
//               -> out_proj GEMM.
// ---------------------------------------------------------------------------

#define BATCH   2
#define SEQLEN  4096
#define DMODEL  1024
#define DINNER  2048
#define E2      4096
#define DSTATE  8
#define DTRANK  64
#define NK      80
#define BL      (BATCH * SEQLEN)

// ---------------------------------------------------------------------------
// Generic NT GEMM: C[M x N] = A[M x K] * B[N x K]^T.
// 64x64 tile, BK=16, 256 threads, 4x4 per thread.
// M (grid.y*64) must be a multiple of 64. N may be ragged (guarded).
// ---------------------------------------------------------------------------
__global__ __launch_bounds__(256) void gemm_nt(
    const float* __restrict__ A, int lda,
    const float* __restrict__ B, int ldb,
    float* __restrict__ C, int ldc,
    int N, int K)
{
    __shared__ float As[16][64];   // [k][m]
    __shared__ float Bs[16][64];   // [k][n]

    const int tid  = threadIdx.x;
    const int tx   = tid & 15;     // n-thread (0..15)
    const int ty   = tid >> 4;     // m-thread (0..15)
    const int bm   = blockIdx.y << 6;
    const int bn   = blockIdx.x << 6;
    const int lrow = tid >> 2;          // 0..63 (tile row for staging)
    const int lcol = (tid & 3) << 2;    // 0/4/8/12 (k offset for staging)

    const float* Aptr = A + (size_t)(bm + lrow) * lda + lcol;
    const float* Bptr = B + (size_t)(bn + lrow) * ldb + lcol;
    const bool   bval = (bn + lrow) < N;

    float acc[4][4] = {};

    for (int k0 = 0; k0 < K; k0 += 16) {
        float4 av = *(const float4*)(Aptr + k0);
        float4 bv = make_float4(0.f, 0.f, 0.f, 0.f);
        if (bval) bv = *(const float4*)(Bptr + k0);

        __syncthreads();   // protect previous iteration's LDS reads
        As[lcol + 0][lrow] = av.x;
        As[lcol + 1][lrow] = av.y;
        As[lcol + 2][lrow] = av.z;
        As[lcol + 3][lrow] = av.w;
        Bs[lcol + 0][lrow] = bv.x;
        Bs[lcol + 1][lrow] = bv.y;
        Bs[lcol + 2][lrow] = bv.z;
        Bs[lcol + 3][lrow] = bv.w;
        __syncthreads();

#pragma unroll
        for (int kk = 0; kk < 16; ++kk) {
            float4 a4 = *(const float4*)&As[kk][ty << 2];
            float4 b4 = *(const float4*)&Bs[kk][tx << 2];
            float ar[4] = {a4.x, a4.y, a4.z, a4.w};
            float br[4] = {b4.x, b4.y, b4.z, b4.w};
#pragma unroll
            for (int i = 0; i < 4; ++i)
#pragma unroll
                for (int j = 0; j < 4; ++j)
                    acc[i][j] = fmaf(ar[i], br[j], acc[i][j]);
        }
    }

    const int cm = bm + (ty << 2);
    const int cn = bn + (tx << 2);
#pragma unroll
    for (int i = 0; i < 4; ++i) {
#pragma unroll
        for (int j = 0; j < 4; ++j) {
            int nn = cn + j;
            if (nn < N)
                C[(size_t)(cm + i) * ldc + nn] = acc[i][j];
        }
    }
}

// ---------------------------------------------------------------------------
// A_eff[d][n] = -exp(A_log[d][n]) + scale * (U[d,:] @ V[:,n]) / sqrt(8)
// ---------------------------------------------------------------------------
__global__ __launch_bounds__(256) void a_eff_kernel(
    const float* __restrict__ A_log, const float* __restrict__ U,
    const float* __restrict__ V, const float* __restrict__ scale_p,
    float* __restrict__ Aeff)
{
    int d = blockIdx.x * 256 + threadIdx.x;
    if (d >= DINNER) return;
    const float s = (*scale_p) * 0.35355339059327378f;  // 1/sqrt(8)
    float ur[8];
#pragma unroll
    for (int r = 0; r < 8; ++r) ur[r] = U[d * 8 + r];
#pragma unroll
    for (int n = 0; n < DSTATE; ++n) {
        float acc = 0.f;
#pragma unroll
        for (int r = 0; r < 8; ++r) acc = fmaf(ur[r], V[r * 8 + n], acc);
        Aeff[d * 8 + n] = -expf(A_log[d * 8 + n]) + s * acc;
    }
}

// ---------------------------------------------------------------------------
// Depthwise causal conv (D_CONV=4) + bias + SiLU.
// Reads x part of xz (cols 0..2047 of (B*L,4096)); writes xt (B*L,2048).
// ---------------------------------------------------------------------------
__global__ __launch_bounds__(256) void conv_silu_kernel(
    const float* __restrict__ xz, const float* __restrict__ cw,
    const float* __restrict__ cb, float* __restrict__ xt)
{
    const int d = blockIdx.x * 256 + threadIdx.x;  // 0..2047
    const int l = blockIdx.y;
    const int b = blockIdx.z;

    float4 w = *(const float4*)&cw[d * 4];
    size_t base = ((size_t)b * SEQLEN + l) * E2 + d;

    float acc = cb[d];
    if (l >= 3) acc = fmaf(w.x, xz[base - 3 * (size_t)E2], acc);
    if (l >= 2) acc = fmaf(w.y, xz[base - 2 * (size_t)E2], acc);
    if (l >= 1) acc = fmaf(w.z, xz[base - 1 * (size_t)E2], acc);
    acc = fmaf(w.w, xz[base], acc);

    float sig = 1.f / (1.f + expf(-acc));
    xt[((size_t)b * SEQLEN + l) * DINNER + d] = acc * sig;
}

// ---------------------------------------------------------------------------
// Selective scan, one thread per (b, d, n).
// Fuses: dt = dt_lr @ dt_proj_w[d,:]  (8 lanes x 8-elem partial dots +
//        shfl reduce), softplus, the h-recurrence, the C-dot, + u*D, and
//        the silu(z) gating. Writes y over the x-half of xz (stride E2).
// block=64 (one wave: 8 d's x 8 n's), grid = B * DINNER/8 = 512.
// ---------------------------------------------------------------------------
__global__ __launch_bounds__(64) void scan_kernel(
    const float* __restrict__ u,       // xt  (B*L, 2048)
    const float* __restrict__ xdbl,    // (B*L, 80)
    const float* __restrict__ xz,      // z read at col 2048+d
    const float* __restrict__ Aeff,    // (2048, 8)
    const float* __restrict__ Dvec,    // (2048,)
    const float* __restrict__ dtw,     // dt_proj_w (2048, 64)
    const float* __restrict__ dtb,     // dt_proj_b (2048,)
    float* __restrict__ yout)          // xz base; y written at col d
{
    const int lane = threadIdx.x;
    const int n    = lane & 7;
    const int b    = blockIdx.x >> 8;          // 256 blocks per batch
    const int d    = (blockIdx.x & 255) * 8 + (lane >> 3);

    const float a    = Aeff[d * 8 + n];
    const float Dd   = Dvec[d];
    const float bias = dtb[d];
    const float4 w0  = *(const float4*)&dtw[d * 64 + n * 8];
    const float4 w1  = *(const float4*)&dtw[d * 64 + n * 8 + 4];

    float h = 0.f;
    size_t rowU = (size_t)b * SEQLEN * DINNER + d;
    size_t rowX = (size_t)b * SEQLEN * NK;
    size_t rowZ = (size_t)b * SEQLEN * E2 + DINNER + d;
    size_t rowY = (size_t)b * SEQLEN * E2 + d;

    for (int t = 0; t < SEQLEN; ++t) {
        float4 g0 = *(const float4*)&xdbl[rowX + n * 8];
        float4 g1 = *(const float4*)&xdbl[rowX + n * 8 + 4];
        float Bn  = xdbl[rowX + DTRANK + n];
        float Cn  = xdbl[rowX + DTRANK + DSTATE + n];
        float ut  = u[rowU];
        float zt  = xz[rowZ];

        // dt = dt_lr[t,:] . dt_proj_w[d,:]  (8-way split over n-lanes)
        float dt = g0.x * w0.x + g0.y * w0.y + g0.z * w0.z + g0.w * w0.w
                 + g1.x * w1.x + g1.y * w1.y + g1.z * w1.z + g1.w * w1.w;
        dt += __shfl_xor(dt, 1);
        dt += __shfl_xor(dt, 2);
        dt += __shfl_xor(dt, 4);
        dt += bias;
        float dl = (dt > 20.f) ? dt : log1pf(expf(dt));

        float dA = expf(dl * a);
        h = fmaf(h, dA, (dl * ut) * Bn);

        float p = h * Cn;
        p += __shfl_xor(p, 1);
        p += __shfl_xor(p, 2);
        p += __shfl_xor(p, 4);

        if (n == 0) {
            float sig = 1.f / (1.f + expf(-zt));
            yout[rowY] = (p + ut * Dd) * (zt * sig);
        }
        rowU += DINNER; rowX += NK; rowZ += E2; rowY += E2;
    }
}

// ---------------------------------------------------------------------------
// Launch
// ---------------------------------------------------------------------------
extern "C" void kernel_launch(void* const* d_in, const int* in_sizes, int n_in,
                              void* d_out, int out_size, void* d_ws, size_t ws_size,
                              hipStream_t stream)
{
    const float* hidden     = (const float*)d_in[0];
    const float* in_proj_w  = (const float*)d_in[1];
    const float* conv_w     = (const float*)d_in[2];
    const float* conv_b     = (const float*)d_in[3];
    const float* x_proj_w   = (const float*)d_in[4];
    const float* dt_proj_w  = (const float*)d_in[5];
    const float* dt_proj_b  = (const float*)d_in[6];
    const float* A_log      = (const float*)d_in[7];
    const float* Dvec       = (const float*)d_in[8];
    const float* out_proj_w = (const float*)d_in[9];
    const float* U_param    = (const float*)d_in[10];
    const float* V_param    = (const float*)d_in[11];
    const float* scale_p    = (const float*)d_in[12];
    float* out = (float*)d_out;

    // d_ws layout (exactly 192 MiB of floats)
    float* ws   = (float*)d_ws;
    float* xz   = ws;                               // 33,554,432 floats
    float* xt   = xz + (size_t)BL * E2;             // 16,777,216 floats

    // d_out doubles as scratch for x_dbl + A_eff until the final GEMM
    float* xdbl = out;                              //    655,360 floats
    float* Aeff = out + (size_t)BL * NK;            //     16,384 floats

    // 1) xz = hidden @ in_proj_w^T        (8192 x 4096, K=1024)
    gemm_nt<<<dim3(E2 / 64, BL / 64), 256, 0, stream>>>(
        hidden, DMODEL, in_proj_w, DMODEL, xz, E2, E2, DMODEL);

    // 2) A_eff -> d_out scratch
    a_eff_kernel<<<dim3(DINNER / 256), 256, 0, stream>>>(
        A_log, U_param, V_param, scale_p, Aeff);

    // 3) depthwise conv + silu -> xt
    conv_silu_kernel<<<dim3(DINNER / 256, SEQLEN, BATCH), 256, 0, stream>>>(
        xz, conv_w, conv_b, xt);

    // 4) x_dbl = xt @ x_proj_w^T          (8192 x 80, K=2048) -> d_out scratch
    gemm_nt<<<dim3((NK + 63) / 64, BL / 64), 256, 0, stream>>>(
        xt, DINNER, x_proj_w, DINNER, xdbl, NK, NK, DINNER);

    // 5) selective scan (fused dt-GEMM + softplus + gating); y -> xz.x half
    scan_kernel<<<dim3(BATCH * DINNER / 8), 64, 0, stream>>>(
        xt, xdbl, xz, Aeff, Dvec, dt_proj_w, dt_proj_b, xz);

    // 6) out = y @ out_proj_w^T           (8192 x 1024, K=2048)
    gemm_nt<<<dim3(DMODEL / 64, BL / 64), 256, 0, stream>>>(
        xz, E2, out_proj_w, DINNER, out, DMODEL, DMODEL, DINNER);
}

// Round 3
// 2893.788 us; speedup vs baseline: 1.7699x; 1.7699x over previous
//
#include <hip/hip_runtime.h>
#include <hip/hip_bf16.h>
#include <math.h>

// ---------------------------------------------------------------------------
// Mamba forward. fp32 GEMMs + chunked (3-phase) selective scan.
// Shapes: B=2, L=4096, D_MODEL=1024, D_INNER=2048, E2=4096, D_STATE=8,
//         D_CONV=4, DT_RANK=64, NK=80 (=64+8+8), R_RANK=8.
//
// d_ws (192 MiB): xz (B*L,4096) [x cols 0..2047 -> y after scan; z 2048..4095]
//                 xt (B*L,2048) (post-conv silu'd == u)
// d_out scratch (until final GEMM overwrites): x_dbl (B*L,80), A_eff (2048,8),
//                 P/H0 and S chunk-state arrays (2 x 524288 floats).
//
// Scan decomposition (exact, linear recurrence):
//   phase1: per chunk c: P_c = prod dA_t, S_c = scan(dBu, h0=0) final state
//   combine: H0_c = running; running = running*P_c + S_c   (in-place over P)
//   phase2: h = H0_c; step recurrence, emit gated y.
// ---------------------------------------------------------------------------

#define BATCH   2
#define SEQLEN  4096
#define DMODEL  1024
#define DINNER  2048
#define E2      4096
#define DSTATE  8
#define DTRANK  64
#define NK      80
#define BL      (BATCH * SEQLEN)
#define CHUNK   256
#define NCHUNK  (SEQLEN / CHUNK)   // 16

// ---------------------------------------------------------------------------
// Generic NT GEMM: C[M x N] = A[M x K] * B[N x K]^T.
// 64x64 tile, BK=16, 256 threads, 4x4 per thread.
// ---------------------------------------------------------------------------
__global__ __launch_bounds__(256) void gemm_nt(
    const float* __restrict__ A, int lda,
    const float* __restrict__ B, int ldb,
    float* __restrict__ C, int ldc,
    int N, int K)
{
    __shared__ float As[16][64];   // [k][m]
    __shared__ float Bs[16][64];   // [k][n]

    const int tid  = threadIdx.x;
    const int tx   = tid & 15;
    const int ty   = tid >> 4;
    const int bm   = blockIdx.y << 6;
    const int bn   = blockIdx.x << 6;
    const int lrow = tid >> 2;
    const int lcol = (tid & 3) << 2;

    const float* Aptr = A + (size_t)(bm + lrow) * lda + lcol;
    const float* Bptr = B + (size_t)(bn + lrow) * ldb + lcol;
    const bool   bval = (bn + lrow) < N;

    float acc[4][4] = {};

    for (int k0 = 0; k0 < K; k0 += 16) {
        float4 av = *(const float4*)(Aptr + k0);
        float4 bv = make_float4(0.f, 0.f, 0.f, 0.f);
        if (bval) bv = *(const float4*)(Bptr + k0);

        __syncthreads();
        As[lcol + 0][lrow] = av.x;
        As[lcol + 1][lrow] = av.y;
        As[lcol + 2][lrow] = av.z;
        As[lcol + 3][lrow] = av.w;
        Bs[lcol + 0][lrow] = bv.x;
        Bs[lcol + 1][lrow] = bv.y;
        Bs[lcol + 2][lrow] = bv.z;
        Bs[lcol + 3][lrow] = bv.w;
        __syncthreads();

#pragma unroll
        for (int kk = 0; kk < 16; ++kk) {
            float4 a4 = *(const float4*)&As[kk][ty << 2];
            float4 b4 = *(const float4*)&Bs[kk][tx << 2];
            float ar[4] = {a4.x, a4.y, a4.z, a4.w};
            float br[4] = {b4.x, b4.y, b4.z, b4.w};
#pragma unroll
            for (int i = 0; i < 4; ++i)
#pragma unroll
                for (int j = 0; j < 4; ++j)
                    acc[i][j] = fmaf(ar[i], br[j], acc[i][j]);
        }
    }

    const int cm = bm + (ty << 2);
    const int cn = bn + (tx << 2);
#pragma unroll
    for (int i = 0; i < 4; ++i) {
#pragma unroll
        for (int j = 0; j < 4; ++j) {
            int nn = cn + j;
            if (nn < N)
                C[(size_t)(cm + i) * ldc + nn] = acc[i][j];
        }
    }
}

// ---------------------------------------------------------------------------
// A_eff[d][n] = -exp(A_log[d][n]) + scale * (U[d,:] @ V[:,n]) / sqrt(8)
// ---------------------------------------------------------------------------
__global__ __launch_bounds__(256) void a_eff_kernel(
    const float* __restrict__ A_log, const float* __restrict__ U,
    const float* __restrict__ V, const float* __restrict__ scale_p,
    float* __restrict__ Aeff)
{
    int d = blockIdx.x * 256 + threadIdx.x;
    if (d >= DINNER) return;
    const float s = (*scale_p) * 0.35355339059327378f;  // 1/sqrt(8)
    float ur[8];
#pragma unroll
    for (int r = 0; r < 8; ++r) ur[r] = U[d * 8 + r];
#pragma unroll
    for (int n = 0; n < DSTATE; ++n) {
        float acc = 0.f;
#pragma unroll
        for (int r = 0; r < 8; ++r) acc = fmaf(ur[r], V[r * 8 + n], acc);
        Aeff[d * 8 + n] = -expf(A_log[d * 8 + n]) + s * acc;
    }
}

// ---------------------------------------------------------------------------
// Depthwise causal conv (D_CONV=4) + bias + SiLU.
// ---------------------------------------------------------------------------
__global__ __launch_bounds__(256) void conv_silu_kernel(
    const float* __restrict__ xz, const float* __restrict__ cw,
    const float* __restrict__ cb, float* __restrict__ xt)
{
    const int d = blockIdx.x * 256 + threadIdx.x;
    const int l = blockIdx.y;
    const int b = blockIdx.z;

    float4 w = *(const float4*)&cw[d * 4];
    size_t base = ((size_t)b * SEQLEN + l) * E2 + d;

    float acc = cb[d];
    if (l >= 3) acc = fmaf(w.x, xz[base - 3 * (size_t)E2], acc);
    if (l >= 2) acc = fmaf(w.y, xz[base - 2 * (size_t)E2], acc);
    if (l >= 1) acc = fmaf(w.z, xz[base - 1 * (size_t)E2], acc);
    acc = fmaf(w.w, xz[base], acc);

    float sig = 1.f / (1.f + expf(-acc));
    xt[((size_t)b * SEQLEN + l) * DINNER + d] = acc * sig;
}

// ---------------------------------------------------------------------------
// Scan phase 1: per-chunk (P, S). Block = 256 threads = 4 waves; each wave
// owns 8 d's x 8 n's for one chunk. grid = (DINNER/32, NCHUNK, BATCH).
// ---------------------------------------------------------------------------
__global__ __launch_bounds__(256) void scan_phase1(
    const float* __restrict__ u,       // xt (B*L, 2048)
    const float* __restrict__ xdbl,    // (B*L, 80)
    const float* __restrict__ Aeff,    // (2048, 8)
    const float* __restrict__ dtw,     // (2048, 64)
    const float* __restrict__ dtb,     // (2048,)
    float* __restrict__ P, float* __restrict__ S)
{
    const int tid  = threadIdx.x;
    const int lane = tid & 63;
    const int wave = tid >> 6;
    const int n    = lane & 7;
    const int d    = blockIdx.x * 32 + wave * 8 + (lane >> 3);
    const int c    = blockIdx.y;
    const int b    = blockIdx.z;

    const float a    = Aeff[d * 8 + n];
    const float bias = dtb[d];
    const float4 w0  = *(const float4*)&dtw[d * 64 + n * 8];
    const float4 w1  = *(const float4*)&dtw[d * 64 + n * 8 + 4];

    const size_t t0 = (size_t)c * CHUNK;
    size_t rowU = ((size_t)b * SEQLEN + t0) * DINNER + d;
    size_t rowX = ((size_t)b * SEQLEN + t0) * NK;

    float Pp = 1.f, Ss = 0.f;
    for (int t = 0; t < CHUNK; ++t) {
        float4 g0 = *(const float4*)&xdbl[rowX + n * 8];
        float4 g1 = *(const float4*)&xdbl[rowX + n * 8 + 4];
        float Bn  = xdbl[rowX + DTRANK + n];
        float ut  = u[rowU];

        float dt = g0.x * w0.x + g0.y * w0.y + g0.z * w0.z + g0.w * w0.w
                 + g1.x * w1.x + g1.y * w1.y + g1.z * w1.z + g1.w * w1.w;
        dt += __shfl_xor(dt, 1);
        dt += __shfl_xor(dt, 2);
        dt += __shfl_xor(dt, 4);
        dt += bias;
        float dl = (dt > 20.f) ? dt : log1pf(expf(dt));

        float dA = expf(dl * a);
        Ss = fmaf(Ss, dA, (dl * ut) * Bn);
        Pp *= dA;
        rowU += DINNER; rowX += NK;
    }
    size_t idx = (((size_t)b * NCHUNK + c) * DINNER + d) * 8 + n;
    P[idx] = Pp;
    S[idx] = Ss;
}

// ---------------------------------------------------------------------------
// Scan combine: sequential over the 16 chunks per (b,d,n).
// Overwrites P with H0 (chunk-entry state).
// ---------------------------------------------------------------------------
__global__ __launch_bounds__(256) void scan_combine(
    float* __restrict__ P, const float* __restrict__ S)
{
    const int i = blockIdx.x * 256 + threadIdx.x;   // over B*DINNER*DSTATE
    if (i >= BATCH * DINNER * DSTATE) return;
    const int b  = i / (DINNER * DSTATE);
    const int dn = i - b * (DINNER * DSTATE);

    float running = 0.f;
#pragma unroll
    for (int c = 0; c < NCHUNK; ++c) {
        size_t idx = (size_t)(b * NCHUNK + c) * (DINNER * DSTATE) + dn;
        float Pc = P[idx];
        float Sc = S[idx];
        P[idx] = running;                 // H0 for chunk c
        running = fmaf(running, Pc, Sc);
    }
}

// ---------------------------------------------------------------------------
// Scan phase 2: full recurrence from H0, emit gated y over xz's x-half.
// ---------------------------------------------------------------------------
__global__ __launch_bounds__(256) void scan_phase2(
    const float* __restrict__ u,
    const float* __restrict__ xdbl,
    const float* __restrict__ xz,      // z at col 2048+d
    const float* __restrict__ Aeff,
    const float* __restrict__ Dvec,
    const float* __restrict__ dtw,
    const float* __restrict__ dtb,
    const float* __restrict__ H0,      // (== P array, post-combine)
    float* __restrict__ yout)          // xz base; y written at col d
{
    const int tid  = threadIdx.x;
    const int lane = tid & 63;
    const int wave = tid >> 6;
    const int n    = lane & 7;
    const int d    = blockIdx.x * 32 + wave * 8 + (lane >> 3);
    const int c    = blockIdx.y;
    const int b    = blockIdx.z;

    const float a    = Aeff[d * 8 + n];
    const float Dd   = Dvec[d];
    const float bias = dtb[d];
    const float4 w0  = *(const float4*)&dtw[d * 64 + n * 8];
    const float4 w1  = *(const float4*)&dtw[d * 64 + n * 8 + 4];

    float h = H0[(((size_t)b * NCHUNK + c) * DINNER + d) * 8 + n];

    const size_t t0 = (size_t)c * CHUNK;
    size_t rowU = ((size_t)b * SEQLEN + t0) * DINNER + d;
    size_t rowX = ((size_t)b * SEQLEN + t0) * NK;
    size_t rowZ = ((size_t)b * SEQLEN + t0) * E2 + DINNER + d;
    size_t rowY = ((size_t)b * SEQLEN + t0) * E2 + d;

    for (int t = 0; t < CHUNK; ++t) {
        float4 g0 = *(const float4*)&xdbl[rowX + n * 8];
        float4 g1 = *(const float4*)&xdbl[rowX + n * 8 + 4];
        float Bn  = xdbl[rowX + DTRANK + n];
        float Cn  = xdbl[rowX + DTRANK + DSTATE + n];
        float ut  = u[rowU];
        float zt  = xz[rowZ];

        float dt = g0.x * w0.x + g0.y * w0.y + g0.z * w0.z + g0.w * w0.w
                 + g1.x * w1.x + g1.y * w1.y + g1.z * w1.z + g1.w * w1.w;
        dt += __shfl_xor(dt, 1);
        dt += __shfl_xor(dt, 2);
        dt += __shfl_xor(dt, 4);
        dt += bias;
        float dl = (dt > 20.f) ? dt : log1pf(expf(dt));

        float dA = expf(dl * a);
        h = fmaf(h, dA, (dl * ut) * Bn);

        float p = h * Cn;
        p += __shfl_xor(p, 1);
        p += __shfl_xor(p, 2);
        p += __shfl_xor(p, 4);

        if (n == 0) {
            float sig = 1.f / (1.f + expf(-zt));
            yout[rowY] = (p + ut * Dd) * (zt * sig);
        }
        rowU += DINNER; rowX += NK; rowZ += E2; rowY += E2;
    }
}

// ---------------------------------------------------------------------------
// Launch
// ---------------------------------------------------------------------------
extern "C" void kernel_launch(void* const* d_in, const int* in_sizes, int n_in,
                              void* d_out, int out_size, void* d_ws, size_t ws_size,
                              hipStream_t stream)
{
    const float* hidden     = (const float*)d_in[0];
    const float* in_proj_w  = (const float*)d_in[1];
    const float* conv_w     = (const float*)d_in[2];
    const float* conv_b     = (const float*)d_in[3];
    const float* x_proj_w   = (const float*)d_in[4];
    const float* dt_proj_w  = (const float*)d_in[5];
    const float* dt_proj_b  = (const float*)d_in[6];
    const float* A_log      = (const float*)d_in[7];
    const float* Dvec       = (const float*)d_in[8];
    const float* out_proj_w = (const float*)d_in[9];
    const float* U_param    = (const float*)d_in[10];
    const float* V_param    = (const float*)d_in[11];
    const float* scale_p    = (const float*)d_in[12];
    float* out = (float*)d_out;

    // d_ws layout (192 MiB)
    float* ws = (float*)d_ws;
    float* xz = ws;                               // 33,554,432 floats
    float* xt = xz + (size_t)BL * E2;             // 16,777,216 floats

    // d_out doubles as scratch until the final GEMM overwrites it
    float* xdbl = out;                            //   655,360 floats
    float* Aeff = xdbl + (size_t)BL * NK;         //    16,384 floats
    float* Parr = Aeff + (size_t)DINNER * DSTATE; //   524,288 floats (-> H0)
    float* Sarr = Parr + (size_t)BATCH * NCHUNK * DINNER * DSTATE; // 524,288

    // 1) xz = hidden @ in_proj_w^T        (8192 x 4096, K=1024)
    gemm_nt<<<dim3(E2 / 64, BL / 64), 256, 0, stream>>>(
        hidden, DMODEL, in_proj_w, DMODEL, xz, E2, E2, DMODEL);

    // 2) A_eff
    a_eff_kernel<<<dim3(DINNER / 256), 256, 0, stream>>>(
        A_log, U_param, V_param, scale_p, Aeff);

    // 3) depthwise conv + silu -> xt
    conv_silu_kernel<<<dim3(DINNER / 256, SEQLEN, BATCH), 256, 0, stream>>>(
        xz, conv_w, conv_b, xt);

    // 4) x_dbl = xt @ x_proj_w^T          (8192 x 80, K=2048)
    gemm_nt<<<dim3((NK + 63) / 64, BL / 64), 256, 0, stream>>>(
        xt, DINNER, x_proj_w, DINNER, xdbl, NK, NK, DINNER);

    // 5) chunked selective scan
    scan_phase1<<<dim3(DINNER / 32, NCHUNK, BATCH), 256, 0, stream>>>(
        xt, xdbl, Aeff, dt_proj_w, dt_proj_b, Parr, Sarr);
    scan_combine<<<dim3((BATCH * DINNER * DSTATE + 255) / 256), 256, 0, stream>>>(
        Parr, Sarr);
    scan_phase2<<<dim3(DINNER / 32, NCHUNK, BATCH), 256, 0, stream>>>(
        xt, xdbl, xz, Aeff, Dvec, dt_proj_w, dt_proj_b, Parr, xz);

    // 6) out = y @ out_proj_w^T           (8192 x 1024, K=2048)
    gemm_nt<<<dim3(DMODEL / 64, BL / 64), 256, 0, stream>>>(
        xz, E2, out_proj_w, DINNER, out, DMODEL, DMODEL, DINNER);
}

// Round 4
// 1802.108 us; speedup vs baseline: 2.8420x; 1.6058x over previous
//
#include <hip/hip_runtime.h>
#include <hip/hip_bf16.h>
#include <math.h>

// ---------------------------------------------------------------------------
// Mamba forward. Split-bf16 (3-pass) MFMA for the two big GEMMs, fp32 GEMM
// for the skinny x_proj, chunked 3-phase selective scan.
// Shapes: B=2, L=4096, D_MODEL=1024, D_INNER=2048, E2=4096, D_STATE=8,
//         D_CONV=4, DT_RANK=64, NK=80, R_RANK=8.
//
// d_ws (192 MiB): xz (B*L,4096) [x cols 0..2047 -> y after scan; z 2048..4095]
//                 xt (B*L,2048) (post-conv silu'd == u)
// d_out scratch (until final GEMM overwrites): x_dbl, A_eff, P/H0, S.
// ---------------------------------------------------------------------------

#define BATCH   2
#define SEQLEN  4096
#define DMODEL  1024
#define DINNER  2048
#define E2      4096
#define DSTATE  8
#define DTRANK  64
#define NK      80
#define BL      (BATCH * SEQLEN)
#define CHUNK   256
#define NCHUNK  (SEQLEN / CHUNK)   // 16

typedef short bf16x8 __attribute__((ext_vector_type(8)));
typedef float f32x4  __attribute__((ext_vector_type(4)));

// RNE float -> bf16 bits (values are finite/normal here; NaN path not needed)
__device__ __forceinline__ unsigned short f2bf(float f) {
    unsigned u = __float_as_uint(f);
    u += 0x7FFF + ((u >> 16) & 1);
    return (unsigned short)(u >> 16);
}
__device__ __forceinline__ float bf2f(unsigned short h) {
    return __uint_as_float((unsigned)h << 16);
}

// ---------------------------------------------------------------------------
// Split-bf16 3-pass MFMA NT GEMM: C[M x N] = A[M x K] * B[N x K]^T, fp32 in/out.
// a*b ~= ah*bh + al*bh + ah*bl  (each mfma_f32_16x16x32_bf16, fp32 acc).
// 128x128 tile, BK=32, 256 threads (4 waves, 64x64 each).
// M, N multiples of 128; K multiple of 32.
// LDS tiles padded to stride 40 ushorts (80B = 5*16B): ds_read_b128 aligned,
// row-phase spread over 8 bank groups -> 2-way max on frag reads (free).
// ---------------------------------------------------------------------------
#define LDST 40

__global__ __launch_bounds__(256) void gemm_nt_bf3(
    const float* __restrict__ A, int lda,
    const float* __restrict__ B, int ldb,
    float* __restrict__ C, int ldc, int K)
{
    __shared__ unsigned short Ah[128 * LDST], Al[128 * LDST];
    __shared__ unsigned short Bh[128 * LDST], Bl[128 * LDST];

    const int tid  = threadIdx.x;
    const int lane = tid & 63;
    const int wave = tid >> 6;
    const int bm   = blockIdx.y << 7;
    const int bn   = blockIdx.x << 7;

    // staging: 256 threads x float4; 32 rows per sweep, 4 sweeps per operand
    const int srow = tid >> 3;         // 0..31
    const int sk4  = (tid & 7) << 2;   // 0,4,...,28

    const float* Ap = A + (size_t)(bm + srow) * lda + sk4;
    const float* Bp = B + (size_t)(bn + srow) * ldb + sk4;

    // compute: wave (wm,wn) owns 64x64; 4x4 fragments of 16x16
    const int wm = (wave >> 1) << 6;
    const int wn = (wave & 1) << 6;
    const int fr = lane & 15;          // frag row (A) / col (B)
    const int kg = lane >> 4;          // k-group of 8

    f32x4 acc[4][4];
#pragma unroll
    for (int i = 0; i < 4; ++i)
#pragma unroll
        for (int j = 0; j < 4; ++j)
            acc[i][j] = (f32x4){0.f, 0.f, 0.f, 0.f};

    for (int k0 = 0; k0 < K; k0 += 32) {
        float4 av[4], bv[4];
#pragma unroll
        for (int i = 0; i < 4; ++i) {
            av[i] = *(const float4*)(Ap + (size_t)(i * 32) * lda + k0);
            bv[i] = *(const float4*)(Bp + (size_t)(i * 32) * ldb + k0);
        }

        __syncthreads();   // previous iteration's frag reads complete
#pragma unroll
        for (int i = 0; i < 4; ++i) {
            const int base = (i * 32 + srow) * LDST + sk4;
            float a0 = av[i].x, a1 = av[i].y, a2 = av[i].z, a3 = av[i].w;
            ushort4 h, l;
            h.x = f2bf(a0); h.y = f2bf(a1); h.z = f2bf(a2); h.w = f2bf(a3);
            l.x = f2bf(a0 - bf2f(h.x)); l.y = f2bf(a1 - bf2f(h.y));
            l.z = f2bf(a2 - bf2f(h.z)); l.w = f2bf(a3 - bf2f(h.w));
            *(ushort4*)&Ah[base] = h;
            *(ushort4*)&Al[base] = l;

            float b0 = bv[i].x, b1 = bv[i].y, b2 = bv[i].z, b3 = bv[i].w;
            h.x = f2bf(b0); h.y = f2bf(b1); h.z = f2bf(b2); h.w = f2bf(b3);
            l.x = f2bf(b0 - bf2f(h.x)); l.y = f2bf(b1 - bf2f(h.y));
            l.z = f2bf(b2 - bf2f(h.z)); l.w = f2bf(b3 - bf2f(h.w));
            *(ushort4*)&Bh[base] = h;
            *(ushort4*)&Bl[base] = l;
        }
        __syncthreads();

        bf16x8 fa_h[4], fa_l[4], fb_h[4], fb_l[4];
#pragma unroll
        for (int f = 0; f < 4; ++f) {
            const int ra = (wm + f * 16 + fr) * LDST + (kg << 3);
            const int rb = (wn + f * 16 + fr) * LDST + (kg << 3);
            fa_h[f] = *(const bf16x8*)&Ah[ra];
            fa_l[f] = *(const bf16x8*)&Al[ra];
            fb_h[f] = *(const bf16x8*)&Bh[rb];
            fb_l[f] = *(const bf16x8*)&Bl[rb];
        }

#pragma unroll
        for (int i = 0; i < 4; ++i)
#pragma unroll
            for (int j = 0; j < 4; ++j) {
                acc[i][j] = __builtin_amdgcn_mfma_f32_16x16x32_bf16(
                    fa_h[i], fb_h[j], acc[i][j], 0, 0, 0);
                acc[i][j] = __builtin_amdgcn_mfma_f32_16x16x32_bf16(
                    fa_l[i], fb_h[j], acc[i][j], 0, 0, 0);
                acc[i][j] = __builtin_amdgcn_mfma_f32_16x16x32_bf16(
                    fa_h[i], fb_l[j], acc[i][j], 0, 0, 0);
            }
    }

    // epilogue: D col = lane&15, row = (lane>>4)*4 + reg   [m89/m91]
    const int erow = (lane >> 4) << 2;
    const int ecol = lane & 15;
#pragma unroll
    for (int i = 0; i < 4; ++i) {
        const int row0 = bm + wm + i * 16 + erow;
#pragma unroll
        for (int j = 0; j < 4; ++j) {
            const int col = bn + wn + j * 16 + ecol;
#pragma unroll
            for (int r = 0; r < 4; ++r)
                C[(size_t)(row0 + r) * ldc + col] = acc[i][j][r];
        }
    }
}

// ---------------------------------------------------------------------------
// fp32 NT GEMM (kept for the skinny x_proj, N=80 ragged).
// ---------------------------------------------------------------------------
__global__ __launch_bounds__(256) void gemm_nt(
    const float* __restrict__ A, int lda,
    const float* __restrict__ B, int ldb,
    float* __restrict__ C, int ldc,
    int N, int K)
{
    __shared__ float As[16][64];
    __shared__ float Bs[16][64];

    const int tid  = threadIdx.x;
    const int tx   = tid & 15;
    const int ty   = tid >> 4;
    const int bm   = blockIdx.y << 6;
    const int bn   = blockIdx.x << 6;
    const int lrow = tid >> 2;
    const int lcol = (tid & 3) << 2;

    const float* Aptr = A + (size_t)(bm + lrow) * lda + lcol;
    const float* Bptr = B + (size_t)(bn + lrow) * ldb + lcol;
    const bool   bval = (bn + lrow) < N;

    float acc[4][4] = {};

    for (int k0 = 0; k0 < K; k0 += 16) {
        float4 av = *(const float4*)(Aptr + k0);
        float4 bv = make_float4(0.f, 0.f, 0.f, 0.f);
        if (bval) bv = *(const float4*)(Bptr + k0);

        __syncthreads();
        As[lcol + 0][lrow] = av.x;
        As[lcol + 1][lrow] = av.y;
        As[lcol + 2][lrow] = av.z;
        As[lcol + 3][lrow] = av.w;
        Bs[lcol + 0][lrow] = bv.x;
        Bs[lcol + 1][lrow] = bv.y;
        Bs[lcol + 2][lrow] = bv.z;
        Bs[lcol + 3][lrow] = bv.w;
        __syncthreads();

#pragma unroll
        for (int kk = 0; kk < 16; ++kk) {
            float4 a4 = *(const float4*)&As[kk][ty << 2];
            float4 b4 = *(const float4*)&Bs[kk][tx << 2];
            float ar[4] = {a4.x, a4.y, a4.z, a4.w};
            float br[4] = {b4.x, b4.y, b4.z, b4.w};
#pragma unroll
            for (int i = 0; i < 4; ++i)
#pragma unroll
                for (int j = 0; j < 4; ++j)
                    acc[i][j] = fmaf(ar[i], br[j], acc[i][j]);
        }
    }

    const int cm = bm + (ty << 2);
    const int cn = bn + (tx << 2);
#pragma unroll
    for (int i = 0; i < 4; ++i) {
#pragma unroll
        for (int j = 0; j < 4; ++j) {
            int nn = cn + j;
            if (nn < N)
                C[(size_t)(cm + i) * ldc + nn] = acc[i][j];
        }
    }
}

// ---------------------------------------------------------------------------
// A_eff[d][n] = -exp(A_log[d][n]) + scale * (U[d,:] @ V[:,n]) / sqrt(8)
// ---------------------------------------------------------------------------
__global__ __launch_bounds__(256) void a_eff_kernel(
    const float* __restrict__ A_log, const float* __restrict__ U,
    const float* __restrict__ V, const float* __restrict__ scale_p,
    float* __restrict__ Aeff)
{
    int d = blockIdx.x * 256 + threadIdx.x;
    if (d >= DINNER) return;
    const float s = (*scale_p) * 0.35355339059327378f;  // 1/sqrt(8)
    float ur[8];
#pragma unroll
    for (int r = 0; r < 8; ++r) ur[r] = U[d * 8 + r];
#pragma unroll
    for (int n = 0; n < DSTATE; ++n) {
        float acc = 0.f;
#pragma unroll
        for (int r = 0; r < 8; ++r) acc = fmaf(ur[r], V[r * 8 + n], acc);
        Aeff[d * 8 + n] = -expf(A_log[d * 8 + n]) + s * acc;
    }
}

// ---------------------------------------------------------------------------
// Depthwise causal conv (D_CONV=4) + bias + SiLU.
// ---------------------------------------------------------------------------
__global__ __launch_bounds__(256) void conv_silu_kernel(
    const float* __restrict__ xz, const float* __restrict__ cw,
    const float* __restrict__ cb, float* __restrict__ xt)
{
    const int d = blockIdx.x * 256 + threadIdx.x;
    const int l = blockIdx.y;
    const int b = blockIdx.z;

    float4 w = *(const float4*)&cw[d * 4];
    size_t base = ((size_t)b * SEQLEN + l) * E2 + d;

    float acc = cb[d];
    if (l >= 3) acc = fmaf(w.x, xz[base - 3 * (size_t)E2], acc);
    if (l >= 2) acc = fmaf(w.y, xz[base - 2 * (size_t)E2], acc);
    if (l >= 1) acc = fmaf(w.z, xz[base - 1 * (size_t)E2], acc);
    acc = fmaf(w.w, xz[base], acc);

    float sig = 1.f / (1.f + expf(-acc));
    xt[((size_t)b * SEQLEN + l) * DINNER + d] = acc * sig;
}

// ---------------------------------------------------------------------------
// Scan phase 1: per-chunk (P, S). 4 waves/block; wave = 8 d's x 8 n's.
// ---------------------------------------------------------------------------
__global__ __launch_bounds__(256) void scan_phase1(
    const float* __restrict__ u,
    const float* __restrict__ xdbl,
    const float* __restrict__ Aeff,
    const float* __restrict__ dtw,
    const float* __restrict__ dtb,
    float* __restrict__ P, float* __restrict__ S)
{
    const int tid  = threadIdx.x;
    const int lane = tid & 63;
    const int wave = tid >> 6;
    const int n    = lane & 7;
    const int d    = blockIdx.x * 32 + wave * 8 + (lane >> 3);
    const int c    = blockIdx.y;
    const int b    = blockIdx.z;

    const float a    = Aeff[d * 8 + n];
    const float bias = dtb[d];
    const float4 w0  = *(const float4*)&dtw[d * 64 + n * 8];
    const float4 w1  = *(const float4*)&dtw[d * 64 + n * 8 + 4];

    const size_t t0 = (size_t)c * CHUNK;
    size_t rowU = ((size_t)b * SEQLEN + t0) * DINNER + d;
    size_t rowX = ((size_t)b * SEQLEN + t0) * NK;

    float Pp = 1.f, Ss = 0.f;
    for (int t = 0; t < CHUNK; ++t) {
        float4 g0 = *(const float4*)&xdbl[rowX + n * 8];
        float4 g1 = *(const float4*)&xdbl[rowX + n * 8 + 4];
        float Bn  = xdbl[rowX + DTRANK + n];
        float ut  = u[rowU];

        float dt = g0.x * w0.x + g0.y * w0.y + g0.z * w0.z + g0.w * w0.w
                 + g1.x * w1.x + g1.y * w1.y + g1.z * w1.z + g1.w * w1.w;
        dt += __shfl_xor(dt, 1);
        dt += __shfl_xor(dt, 2);
        dt += __shfl_xor(dt, 4);
        dt += bias;
        float dl = (dt > 20.f) ? dt : log1pf(expf(dt));

        float dA = expf(dl * a);
        Ss = fmaf(Ss, dA, (dl * ut) * Bn);
        Pp *= dA;
        rowU += DINNER; rowX += NK;
    }
    size_t idx = (((size_t)b * NCHUNK + c) * DINNER + d) * 8 + n;
    P[idx] = Pp;
    S[idx] = Ss;
}

// ---------------------------------------------------------------------------
// Scan combine: sequential over 16 chunks per (b,d,n). P <- H0 in place.
// ---------------------------------------------------------------------------
__global__ __launch_bounds__(256) void scan_combine(
    float* __restrict__ P, const float* __restrict__ S)
{
    const int i = blockIdx.x * 256 + threadIdx.x;
    if (i >= BATCH * DINNER * DSTATE) return;
    const int b  = i / (DINNER * DSTATE);
    const int dn = i - b * (DINNER * DSTATE);

    float running = 0.f;
#pragma unroll
    for (int c = 0; c < NCHUNK; ++c) {
        size_t idx = (size_t)(b * NCHUNK + c) * (DINNER * DSTATE) + dn;
        float Pc = P[idx];
        float Sc = S[idx];
        P[idx] = running;
        running = fmaf(running, Pc, Sc);
    }
}

// ---------------------------------------------------------------------------
// Scan phase 2: full recurrence from H0, emit gated y over xz's x-half.
// ---------------------------------------------------------------------------
__global__ __launch_bounds__(256) void scan_phase2(
    const float* __restrict__ u,
    const float* __restrict__ xdbl,
    const float* __restrict__ xz,
    const float* __restrict__ Aeff,
    const float* __restrict__ Dvec,
    const float* __restrict__ dtw,
    const float* __restrict__ dtb,
    const float* __restrict__ H0,
    float* __restrict__ yout)
{
    const int tid  = threadIdx.x;
    const int lane = tid & 63;
    const int wave = tid >> 6;
    const int n    = lane & 7;
    const int d    = blockIdx.x * 32 + wave * 8 + (lane >> 3);
    const int c    = blockIdx.y;
    const int b    = blockIdx.z;

    const float a    = Aeff[d * 8 + n];
    const float Dd   = Dvec[d];
    const float bias = dtb[d];
    const float4 w0  = *(const float4*)&dtw[d * 64 + n * 8];
    const float4 w1  = *(const float4*)&dtw[d * 64 + n * 8 + 4];

    float h = H0[(((size_t)b * NCHUNK + c) * DINNER + d) * 8 + n];

    const size_t t0 = (size_t)c * CHUNK;
    size_t rowU = ((size_t)b * SEQLEN + t0) * DINNER + d;
    size_t rowX = ((size_t)b * SEQLEN + t0) * NK;
    size_t rowZ = ((size_t)b * SEQLEN + t0) * E2 + DINNER + d;
    size_t rowY = ((size_t)b * SEQLEN + t0) * E2 + d;

    for (int t = 0; t < CHUNK; ++t) {
        float4 g0 = *(const float4*)&xdbl[rowX + n * 8];
        float4 g1 = *(const float4*)&xdbl[rowX + n * 8 + 4];
        float Bn  = xdbl[rowX + DTRANK + n];
        float Cn  = xdbl[rowX + DTRANK + DSTATE + n];
        float ut  = u[rowU];
        float zt  = xz[rowZ];

        float dt = g0.x * w0.x + g0.y * w0.y + g0.z * w0.z + g0.w * w0.w
                 + g1.x * w1.x + g1.y * w1.y + g1.z * w1.z + g1.w * w1.w;
        dt += __shfl_xor(dt, 1);
        dt += __shfl_xor(dt, 2);
        dt += __shfl_xor(dt, 4);
        dt += bias;
        float dl = (dt > 20.f) ? dt : log1pf(expf(dt));

        float dA = expf(dl * a);
        h = fmaf(h, dA, (dl * ut) * Bn);

        float p = h * Cn;
        p += __shfl_xor(p, 1);
        p += __shfl_xor(p, 2);
        p += __shfl_xor(p, 4);

        if (n == 0) {
            float sig = 1.f / (1.f + expf(-zt));
            yout[rowY] = (p + ut * Dd) * (zt * sig);
        }
        rowU += DINNER; rowX += NK; rowZ += E2; rowY += E2;
    }
}

// ---------------------------------------------------------------------------
// Launch
// ---------------------------------------------------------------------------
extern "C" void kernel_launch(void* const* d_in, const int* in_sizes, int n_in,
                              void* d_out, int out_size, void* d_ws, size_t ws_size,
                              hipStream_t stream)
{
    const float* hidden     = (const float*)d_in[0];
    const float* in_proj_w  = (const float*)d_in[1];
    const float* conv_w     = (const float*)d_in[2];
    const float* conv_b     = (const float*)d_in[3];
    const float* x_proj_w   = (const float*)d_in[4];
    const float* dt_proj_w  = (const float*)d_in[5];
    const float* dt_proj_b  = (const float*)d_in[6];
    const float* A_log      = (const float*)d_in[7];
    const float* Dvec       = (const float*)d_in[8];
    const float* out_proj_w = (const float*)d_in[9];
    const float* U_param    = (const float*)d_in[10];
    const float* V_param    = (const float*)d_in[11];
    const float* scale_p    = (const float*)d_in[12];
    float* out = (float*)d_out;

    // d_ws layout (192 MiB)
    float* ws = (float*)d_ws;
    float* xz = ws;                               // 33,554,432 floats
    float* xt = xz + (size_t)BL * E2;             // 16,777,216 floats

    // d_out doubles as scratch until the final GEMM overwrites it
    float* xdbl = out;                            //   655,360 floats
    float* Aeff = xdbl + (size_t)BL * NK;         //    16,384 floats
    float* Parr = Aeff + (size_t)DINNER * DSTATE; //   524,288 floats (-> H0)
    float* Sarr = Parr + (size_t)BATCH * NCHUNK * DINNER * DSTATE; // 524,288

    // 1) xz = hidden @ in_proj_w^T        (8192 x 4096, K=1024)  [MFMA 3-pass]
    gemm_nt_bf3<<<dim3(E2 / 128, BL / 128), 256, 0, stream>>>(
        hidden, DMODEL, in_proj_w, DMODEL, xz, E2, DMODEL);

    // 2) A_eff
    a_eff_kernel<<<dim3(DINNER / 256), 256, 0, stream>>>(
        A_log, U_param, V_param, scale_p, Aeff);

    // 3) depthwise conv + silu -> xt
    conv_silu_kernel<<<dim3(DINNER / 256, SEQLEN, BATCH), 256, 0, stream>>>(
        xz, conv_w, conv_b, xt);

    // 4) x_dbl = xt @ x_proj_w^T          (8192 x 80, K=2048)  [fp32]
    gemm_nt<<<dim3((NK + 63) / 64, BL / 64), 256, 0, stream>>>(
        xt, DINNER, x_proj_w, DINNER, xdbl, NK, NK, DINNER);

    // 5) chunked selective scan
    scan_phase1<<<dim3(DINNER / 32, NCHUNK, BATCH), 256, 0, stream>>>(
        xt, xdbl, Aeff, dt_proj_w, dt_proj_b, Parr, Sarr);
    scan_combine<<<dim3((BATCH * DINNER * DSTATE + 255) / 256), 256, 0, stream>>>(
        Parr, Sarr);
    scan_phase2<<<dim3(DINNER / 32, NCHUNK, BATCH), 256, 0, stream>>>(
        xt, xdbl, xz, Aeff, Dvec, dt_proj_w, dt_proj_b, Parr, xz);

    // 6) out = y @ out_proj_w^T           (8192 x 1024, K=2048)  [MFMA 3-pass]
    gemm_nt_bf3<<<dim3(DMODEL / 128, BL / 128), 256, 0, stream>>>(
        xz, E2, out_proj_w, DINNER, out, DMODEL, DINNER);
}

// Round 5
// 1026.475 us; speedup vs baseline: 4.9895x; 1.7556x over previous
//
#include <hip/hip_runtime.h>
#include <hip/hip_bf16.h>
#include <math.h>

// ---------------------------------------------------------------------------
// Mamba forward. Split-bf16 (3-pass) MFMA GEMMs (in_proj, x_proj, out_proj),
// fp32 GEMM w/ softplus epilogue for delta, chunked 3-phase selective scan
// that STREAMS a precomputed delta (no per-step dt recompute).
// Shapes: B=2, L=4096, D_MODEL=1024, D_INNER=2048, E2=4096, D_STATE=8,
//         D_CONV=4, DT_RANK=64, NK=80, R_RANK=8.
//
// d_ws (192 MiB): xz (B*L,4096) [x cols 0..2047: x -> (conv) dead -> delta
//                  -> overwritten in-place by y during phase2; z 2048..4095]
//                 xt (B*L,2048) (post-conv silu'd == u)
// d_out scratch (until final GEMM overwrites): x_dbl, A_eff, P/H0, S.
// ---------------------------------------------------------------------------

#define BATCH   2
#define SEQLEN  4096
#define DMODEL  1024
#define DINNER  2048
#define E2      4096
#define DSTATE  8
#define DTRANK  64
#define NK      80
#define BL      (BATCH * SEQLEN)
#define CHUNK   256
#define NCHUNK  (SEQLEN / CHUNK)   // 16

typedef short bf16x8 __attribute__((ext_vector_type(8)));
typedef float f32x4  __attribute__((ext_vector_type(4)));

// RNE float -> bf16 bits
__device__ __forceinline__ unsigned short f2bf(float f) {
    unsigned u = __float_as_uint(f);
    u += 0x7FFF + ((u >> 16) & 1);
    return (unsigned short)(u >> 16);
}
__device__ __forceinline__ float bf2f(unsigned short h) {
    return __uint_as_float((unsigned)h << 16);
}

// ---------------------------------------------------------------------------
// Split-bf16 3-pass MFMA NT GEMM: C[M x N] = A[M x K] * B[N x K]^T, fp32 io.
// a*b ~= ah*bh + al*bh + ah*bl. 128x128 tile, BK=32, 4 waves.
// M multiple of 128, K multiple of 32. N ragged (B-row + store guards).
// ---------------------------------------------------------------------------
#define LDST 40

__global__ __launch_bounds__(256) void gemm_nt_bf3(
    const float* __restrict__ A, int lda,
    const float* __restrict__ B, int ldb,
    float* __restrict__ C, int ldc, int N, int K)
{
    __shared__ unsigned short Ah[128 * LDST], Al[128 * LDST];
    __shared__ unsigned short Bh[128 * LDST], Bl[128 * LDST];

    const int tid  = threadIdx.x;
    const int lane = tid & 63;
    const int wave = tid >> 6;
    const int bm   = blockIdx.y << 7;
    const int bn   = blockIdx.x << 7;

    const int srow = tid >> 3;         // 0..31
    const int sk4  = (tid & 7) << 2;   // 0,4,...,28

    const float* Ap = A + (size_t)(bm + srow) * lda + sk4;
    const float* Bp = B + (size_t)(bn + srow) * ldb + sk4;

    const int wm = (wave >> 1) << 6;
    const int wn = (wave & 1) << 6;
    const int fr = lane & 15;
    const int kg = lane >> 4;

    f32x4 acc[4][4];
#pragma unroll
    for (int i = 0; i < 4; ++i)
#pragma unroll
        for (int j = 0; j < 4; ++j)
            acc[i][j] = (f32x4){0.f, 0.f, 0.f, 0.f};

    for (int k0 = 0; k0 < K; k0 += 32) {
        float4 av[4], bv[4];
#pragma unroll
        for (int i = 0; i < 4; ++i) {
            av[i] = *(const float4*)(Ap + (size_t)(i * 32) * lda + k0);
            bv[i] = make_float4(0.f, 0.f, 0.f, 0.f);
            if (bn + srow + i * 32 < N)
                bv[i] = *(const float4*)(Bp + (size_t)(i * 32) * ldb + k0);
        }

        __syncthreads();
#pragma unroll
        for (int i = 0; i < 4; ++i) {
            const int base = (i * 32 + srow) * LDST + sk4;
            float a0 = av[i].x, a1 = av[i].y, a2 = av[i].z, a3 = av[i].w;
            ushort4 h, l;
            h.x = f2bf(a0); h.y = f2bf(a1); h.z = f2bf(a2); h.w = f2bf(a3);
            l.x = f2bf(a0 - bf2f(h.x)); l.y = f2bf(a1 - bf2f(h.y));
            l.z = f2bf(a2 - bf2f(h.z)); l.w = f2bf(a3 - bf2f(h.w));
            *(ushort4*)&Ah[base] = h;
            *(ushort4*)&Al[base] = l;

            float b0 = bv[i].x, b1 = bv[i].y, b2 = bv[i].z, b3 = bv[i].w;
            h.x = f2bf(b0); h.y = f2bf(b1); h.z = f2bf(b2); h.w = f2bf(b3);
            l.x = f2bf(b0 - bf2f(h.x)); l.y = f2bf(b1 - bf2f(h.y));
            l.z = f2bf(b2 - bf2f(h.z)); l.w = f2bf(b3 - bf2f(h.w));
            *(ushort4*)&Bh[base] = h;
            *(ushort4*)&Bl[base] = l;
        }
        __syncthreads();

        bf16x8 fa_h[4], fa_l[4], fb_h[4], fb_l[4];
#pragma unroll
        for (int f = 0; f < 4; ++f) {
            const int ra = (wm + f * 16 + fr) * LDST + (kg << 3);
            const int rb = (wn + f * 16 + fr) * LDST + (kg << 3);
            fa_h[f] = *(const bf16x8*)&Ah[ra];
            fa_l[f] = *(const bf16x8*)&Al[ra];
            fb_h[f] = *(const bf16x8*)&Bh[rb];
            fb_l[f] = *(const bf16x8*)&Bl[rb];
        }

#pragma unroll
        for (int i = 0; i < 4; ++i)
#pragma unroll
            for (int j = 0; j < 4; ++j) {
                acc[i][j] = __builtin_amdgcn_mfma_f32_16x16x32_bf16(
                    fa_h[i], fb_h[j], acc[i][j], 0, 0, 0);
                acc[i][j] = __builtin_amdgcn_mfma_f32_16x16x32_bf16(
                    fa_l[i], fb_h[j], acc[i][j], 0, 0, 0);
                acc[i][j] = __builtin_amdgcn_mfma_f32_16x16x32_bf16(
                    fa_h[i], fb_l[j], acc[i][j], 0, 0, 0);
            }
    }

    const int erow = (lane >> 4) << 2;
    const int ecol = lane & 15;
#pragma unroll
    for (int i = 0; i < 4; ++i) {
        const int row0 = bm + wm + i * 16 + erow;
#pragma unroll
        for (int j = 0; j < 4; ++j) {
            const int col = bn + wn + j * 16 + ecol;
            if (col < N) {
#pragma unroll
                for (int r = 0; r < 4; ++r)
                    C[(size_t)(row0 + r) * ldc + col] = acc[i][j][r];
            }
        }
    }
}

// ---------------------------------------------------------------------------
// fp32 NT GEMM. EPI: 0 = plain, 1 = softplus(acc + bias[n]).
// Used only for the delta GEMM (K=64) where fp32 precision is kept.
// ---------------------------------------------------------------------------
template <int EPI>
__global__ __launch_bounds__(256) void gemm_nt(
    const float* __restrict__ A, int lda,
    const float* __restrict__ B, int ldb,
    const float* __restrict__ bias,
    float* __restrict__ C, int ldc,
    int N, int K)
{
    __shared__ float As[16][64];
    __shared__ float Bs[16][64];

    const int tid  = threadIdx.x;
    const int tx   = tid & 15;
    const int ty   = tid >> 4;
    const int bm   = blockIdx.y << 6;
    const int bn   = blockIdx.x << 6;
    const int lrow = tid >> 2;
    const int lcol = (tid & 3) << 2;

    const float* Aptr = A + (size_t)(bm + lrow) * lda + lcol;
    const float* Bptr = B + (size_t)(bn + lrow) * ldb + lcol;
    const bool   bval = (bn + lrow) < N;

    float acc[4][4] = {};

    for (int k0 = 0; k0 < K; k0 += 16) {
        float4 av = *(const float4*)(Aptr + k0);
        float4 bv = make_float4(0.f, 0.f, 0.f, 0.f);
        if (bval) bv = *(const float4*)(Bptr + k0);

        __syncthreads();
        As[lcol + 0][lrow] = av.x;
        As[lcol + 1][lrow] = av.y;
        As[lcol + 2][lrow] = av.z;
        As[lcol + 3][lrow] = av.w;
        Bs[lcol + 0][lrow] = bv.x;
        Bs[lcol + 1][lrow] = bv.y;
        Bs[lcol + 2][lrow] = bv.z;
        Bs[lcol + 3][lrow] = bv.w;
        __syncthreads();

#pragma unroll
        for (int kk = 0; kk < 16; ++kk) {
            float4 a4 = *(const float4*)&As[kk][ty << 2];
            float4 b4 = *(const float4*)&Bs[kk][tx << 2];
            float ar[4] = {a4.x, a4.y, a4.z, a4.w};
            float br[4] = {b4.x, b4.y, b4.z, b4.w};
#pragma unroll
            for (int i = 0; i < 4; ++i)
#pragma unroll
                for (int j = 0; j < 4; ++j)
                    acc[i][j] = fmaf(ar[i], br[j], acc[i][j]);
        }
    }

    const int cm = bm + (ty << 2);
    const int cn = bn + (tx << 2);
#pragma unroll
    for (int i = 0; i < 4; ++i) {
#pragma unroll
        for (int j = 0; j < 4; ++j) {
            int nn = cn + j;
            if (nn < N) {
                float v = acc[i][j];
                if (EPI == 1) {
                    v += bias[nn];
                    v = (v > 20.f) ? v : log1pf(expf(v));
                }
                C[(size_t)(cm + i) * ldc + nn] = v;
            }
        }
    }
}

// ---------------------------------------------------------------------------
// A_eff[d][n] = -exp(A_log[d][n]) + scale * (U[d,:] @ V[:,n]) / sqrt(8)
// ---------------------------------------------------------------------------
__global__ __launch_bounds__(256) void a_eff_kernel(
    const float* __restrict__ A_log, const float* __restrict__ U,
    const float* __restrict__ V, const float* __restrict__ scale_p,
    float* __restrict__ Aeff)
{
    int d = blockIdx.x * 256 + threadIdx.x;
    if (d >= DINNER) return;
    const float s = (*scale_p) * 0.35355339059327378f;  // 1/sqrt(8)
    float ur[8];
#pragma unroll
    for (int r = 0; r < 8; ++r) ur[r] = U[d * 8 + r];
#pragma unroll
    for (int n = 0; n < DSTATE; ++n) {
        float acc = 0.f;
#pragma unroll
        for (int r = 0; r < 8; ++r) acc = fmaf(ur[r], V[r * 8 + n], acc);
        Aeff[d * 8 + n] = -expf(A_log[d * 8 + n]) + s * acc;
    }
}

// ---------------------------------------------------------------------------
// Depthwise causal conv (D_CONV=4) + bias + SiLU.
// ---------------------------------------------------------------------------
__global__ __launch_bounds__(256) void conv_silu_kernel(
    const float* __restrict__ xz, const float* __restrict__ cw,
    const float* __restrict__ cb, float* __restrict__ xt)
{
    const int d = blockIdx.x * 256 + threadIdx.x;
    const int l = blockIdx.y;
    const int b = blockIdx.z;

    float4 w = *(const float4*)&cw[d * 4];
    size_t base = ((size_t)b * SEQLEN + l) * E2 + d;

    float acc = cb[d];
    if (l >= 3) acc = fmaf(w.x, xz[base - 3 * (size_t)E2], acc);
    if (l >= 2) acc = fmaf(w.y, xz[base - 2 * (size_t)E2], acc);
    if (l >= 1) acc = fmaf(w.z, xz[base - 1 * (size_t)E2], acc);
    acc = fmaf(w.w, xz[base], acc);

    float sig = 1.f / (1.f + expf(-acc));
    xt[((size_t)b * SEQLEN + l) * DINNER + d] = acc * sig;
}

// ---------------------------------------------------------------------------
// Scan phase 1: per-chunk (P, S), streaming precomputed delta.
// P = exp(a * sum(dl)) (chunk-end), S = local recurrence from h0=0.
// 4 waves/block; wave = 8 d's x 8 n's. grid = (DINNER/32, NCHUNK, BATCH).
// ---------------------------------------------------------------------------
__global__ __launch_bounds__(256) void scan_phase1(
    const float* __restrict__ delta,   // xz base; dl at col d, stride E2
    const float* __restrict__ u,       // xt (B*L, 2048)
    const float* __restrict__ xdbl,    // (B*L, 80)
    const float* __restrict__ Aeff,    // (2048, 8)
    float* __restrict__ P, float* __restrict__ S)
{
    const int tid  = threadIdx.x;
    const int lane = tid & 63;
    const int wave = tid >> 6;
    const int n    = lane & 7;
    const int d    = blockIdx.x * 32 + wave * 8 + (lane >> 3);
    const int c    = blockIdx.y;
    const int b    = blockIdx.z;

    const float a = Aeff[d * 8 + n];

    const size_t t0 = (size_t)c * CHUNK;
    size_t rowD = ((size_t)b * SEQLEN + t0) * E2 + d;
    size_t rowU = ((size_t)b * SEQLEN + t0) * DINNER + d;
    size_t rowX = ((size_t)b * SEQLEN + t0) * NK;

    float Ss = 0.f, sdl = 0.f;
    for (int t = 0; t < CHUNK; ++t) {
        float dl = delta[rowD];
        float ut = u[rowU];
        float Bn = xdbl[rowX + DTRANK + n];

        float dA = expf(dl * a);
        Ss = fmaf(Ss, dA, (dl * ut) * Bn);
        sdl += dl;
        rowD += E2; rowU += DINNER; rowX += NK;
    }
    size_t idx = (((size_t)b * NCHUNK + c) * DINNER + d) * 8 + n;
    P[idx] = expf(sdl * a);
    S[idx] = Ss;
}

// ---------------------------------------------------------------------------
// Scan combine: sequential over 16 chunks per (b,d,n). P <- H0 in place.
// ---------------------------------------------------------------------------
__global__ __launch_bounds__(256) void scan_combine(
    float* __restrict__ P, const float* __restrict__ S)
{
    const int i = blockIdx.x * 256 + threadIdx.x;
    if (i >= BATCH * DINNER * DSTATE) return;
    const int b  = i / (DINNER * DSTATE);
    const int dn = i - b * (DINNER * DSTATE);

    float running = 0.f;
#pragma unroll
    for (int c = 0; c < NCHUNK; ++c) {
        size_t idx = (size_t)(b * NCHUNK + c) * (DINNER * DSTATE) + dn;
        float Pc = P[idx];
        float Sc = S[idx];
        P[idx] = running;
        running = fmaf(running, Pc, Sc);
    }
}

// ---------------------------------------------------------------------------
// Scan phase 2: recurrence from H0, streaming delta; gated y overwrites
// delta in place (same (t,d) element, read-before-write within the wave).
// ---------------------------------------------------------------------------
__global__ __launch_bounds__(256) void scan_phase2(
    float* __restrict__ deltay,        // xz base; delta read / y write, col d
    const float* __restrict__ u,
    const float* __restrict__ xdbl,
    const float* __restrict__ xz,      // z at col 2048+d
    const float* __restrict__ Aeff,
    const float* __restrict__ Dvec,
    const float* __restrict__ H0)
{
    const int tid  = threadIdx.x;
    const int lane = tid & 63;
    const int wave = tid >> 6;
    const int n    = lane & 7;
    const int d    = blockIdx.x * 32 + wave * 8 + (lane >> 3);
    const int c    = blockIdx.y;
    const int b    = blockIdx.z;

    const float a  = Aeff[d * 8 + n];
    const float Dd = Dvec[d];

    float h = H0[(((size_t)b * NCHUNK + c) * DINNER + d) * 8 + n];

    const size_t t0 = (size_t)c * CHUNK;
    size_t rowD = ((size_t)b * SEQLEN + t0) * E2 + d;
    size_t rowU = ((size_t)b * SEQLEN + t0) * DINNER + d;
    size_t rowX = ((size_t)b * SEQLEN + t0) * NK;
    size_t rowZ = ((size_t)b * SEQLEN + t0) * E2 + DINNER + d;

    for (int t = 0; t < CHUNK; ++t) {
        float dl = deltay[rowD];
        float ut = u[rowU];
        float Bn = xdbl[rowX + DTRANK + n];
        float Cn = xdbl[rowX + DTRANK + DSTATE + n];
        float zt = xz[rowZ];

        float dA = expf(dl * a);
        h = fmaf(h, dA, (dl * ut) * Bn);

        float p = h * Cn;
        p += __shfl_xor(p, 1);
        p += __shfl_xor(p, 2);
        p += __shfl_xor(p, 4);

        if (n == 0) {
            float sig = 1.f / (1.f + expf(-zt));
            deltay[rowD] = (p + ut * Dd) * (zt * sig);
        }
        rowD += E2; rowU += DINNER; rowX += NK; rowZ += E2;
    }
}

// ---------------------------------------------------------------------------
// Launch
// ---------------------------------------------------------------------------
extern "C" void kernel_launch(void* const* d_in, const int* in_sizes, int n_in,
                              void* d_out, int out_size, void* d_ws, size_t ws_size,
                              hipStream_t stream)
{
    const float* hidden     = (const float*)d_in[0];
    const float* in_proj_w  = (const float*)d_in[1];
    const float* conv_w     = (const float*)d_in[2];
    const float* conv_b     = (const float*)d_in[3];
    const float* x_proj_w   = (const float*)d_in[4];
    const float* dt_proj_w  = (const float*)d_in[5];
    const float* dt_proj_b  = (const float*)d_in[6];
    const float* A_log      = (const float*)d_in[7];
    const float* Dvec       = (const float*)d_in[8];
    const float* out_proj_w = (const float*)d_in[9];
    const float* U_param    = (const float*)d_in[10];
    const float* V_param    = (const float*)d_in[11];
    const float* scale_p    = (const float*)d_in[12];
    float* out = (float*)d_out;

    // d_ws layout (192 MiB)
    float* ws = (float*)d_ws;
    float* xz = ws;                               // 33,554,432 floats
    float* xt = xz + (size_t)BL * E2;             // 16,777,216 floats

    // d_out doubles as scratch until the final GEMM overwrites it
    float* xdbl = out;                            //   655,360 floats
    float* Aeff = xdbl + (size_t)BL * NK;         //    16,384 floats
    float* Parr = Aeff + (size_t)DINNER * DSTATE; //   524,288 floats (-> H0)
    float* Sarr = Parr + (size_t)BATCH * NCHUNK * DINNER * DSTATE; // 524,288

    // 1) xz = hidden @ in_proj_w^T        (8192 x 4096, K=1024)  [MFMA bf3]
    gemm_nt_bf3<<<dim3(E2 / 128, BL / 128), 256, 0, stream>>>(
        hidden, DMODEL, in_proj_w, DMODEL, xz, E2, E2, DMODEL);

    // 2) A_eff
    a_eff_kernel<<<dim3(DINNER / 256), 256, 0, stream>>>(
        A_log, U_param, V_param, scale_p, Aeff);

    // 3) depthwise conv + silu -> xt   (consumes xz.x; x now dead)
    conv_silu_kernel<<<dim3(DINNER / 256, SEQLEN, BATCH), 256, 0, stream>>>(
        xz, conv_w, conv_b, xt);

    // 4) x_dbl = xt @ x_proj_w^T          (8192 x 80, K=2048)  [MFMA bf3]
    gemm_nt_bf3<<<dim3((NK + 127) / 128, BL / 128), 256, 0, stream>>>(
        xt, DINNER, x_proj_w, DINNER, xdbl, NK, NK, DINNER);

    // 5) delta = softplus(dt_lr @ dt_proj_w^T + b) -> xz.x half (ldc=E2) [fp32]
    gemm_nt<1><<<dim3(DINNER / 64, BL / 64), 256, 0, stream>>>(
        xdbl, NK, dt_proj_w, DTRANK, dt_proj_b, xz, E2, DINNER, DTRANK);

    // 6) chunked selective scan (streams delta; y overwrites delta in place)
    scan_phase1<<<dim3(DINNER / 32, NCHUNK, BATCH), 256, 0, stream>>>(
        xz, xt, xdbl, Aeff, Parr, Sarr);
    scan_combine<<<dim3((BATCH * DINNER * DSTATE + 255) / 256), 256, 0, stream>>>(
        Parr, Sarr);
    scan_phase2<<<dim3(DINNER / 32, NCHUNK, BATCH), 256, 0, stream>>>(
        xz, xt, xdbl, xz, Aeff, Dvec, Parr);

    // 7) out = y @ out_proj_w^T           (8192 x 1024, K=2048)  [MFMA bf3]
    gemm_nt_bf3<<<dim3(DMODEL / 128, BL / 128), 256, 0, stream>>>(
        xz, E2, out_proj_w, DINNER, out, DMODEL, DMODEL, DINNER);
}

// Round 7
// 993.180 us; speedup vs baseline: 5.1567x; 1.0335x over previous
//
#include <hip/hip_runtime.h>
#include <hip/hip_bf16.h>
#include <math.h>

// ---------------------------------------------------------------------------
// Mamba forward. Planar split-bf16 (3-pass) MFMA GEMMs with PRE-SPLIT
// operands (no fp32->bf16 conversion inside GEMM inner loops), fp32 GEMM w/
// softplus epilogue for delta, chunked 3-phase selective scan.
// Shapes: B=2, L=4096, D_MODEL=1024, D_INNER=2048, E2=4096, D_STATE=8,
//         D_CONV=4, DT_RANK=64, NK=80, R_RANK=8.
//
// d_ws (192 MiB): xbuf (BL,2048) fp32  [x -> conv -> dead -> delta -> y(pk)]
//                 zbuf (BL,2048) fp32  [z; after phase2: out_proj_w splits]
//                 xth/xtl (BL,2048) ushort planes  [in_proj_w splits first,
//                                                   then u hi/lo from conv]
// d_out scratch: hidden hi/lo splits (GEMM1), then xdbl/Aeff/P/S/xpw splits.
// ---------------------------------------------------------------------------

#define BATCH   2
#define SEQLEN  4096
#define DMODEL  1024
#define DINNER  2048
#define E2      4096
#define DSTATE  8
#define DTRANK  64
#define NK      80
#define BL      (BATCH * SEQLEN)
#define CHUNK   256
#define NCHUNK  (SEQLEN / CHUNK)   // 16

typedef short bf16x8 __attribute__((ext_vector_type(8)));
typedef float f32x4  __attribute__((ext_vector_type(4)));
typedef unsigned short ushort8 __attribute__((ext_vector_type(8)));

__device__ __forceinline__ unsigned short f2bf(float f) {
    unsigned u = __float_as_uint(f);
    u += 0x7FFF + ((u >> 16) & 1);
    return (unsigned short)(u >> 16);
}
__device__ __forceinline__ float bf2f(unsigned short h) {
    return __uint_as_float((unsigned)h << 16);
}

// ---------------------------------------------------------------------------
// Elementwise fp32 -> planar (hi, lo) bf16 split. n4 = n/4 float4 groups.
// ---------------------------------------------------------------------------
__global__ __launch_bounds__(256) void split_kernel(
    const float* __restrict__ src,
    unsigned short* __restrict__ hi, unsigned short* __restrict__ lo, int n4)
{
    int i = blockIdx.x * 256 + threadIdx.x;
    if (i >= n4) return;
    float4 v = ((const float4*)src)[i];
    ushort4 h, l;
    h.x = f2bf(v.x); h.y = f2bf(v.y); h.z = f2bf(v.z); h.w = f2bf(v.w);
    l.x = f2bf(v.x - bf2f(h.x)); l.y = f2bf(v.y - bf2f(h.y));
    l.z = f2bf(v.z - bf2f(h.z)); l.w = f2bf(v.w - bf2f(h.w));
    ((ushort4*)hi)[i] = h;
    ((ushort4*)lo)[i] = l;
}

// ---------------------------------------------------------------------------
// Planar split-bf16 3-pass MFMA NT GEMM. C = A * B^T, fp32 accumulate.
// APK=0: A given as planar hi/lo ushort arrays. APK=1: A packed uint
//        (hi<<16|lo) -- used for the scan's y output.
// SPLITC=1: N-split C store (cols < DINNER -> C0, else -> C1), ldc both.
// 128x128 tile, BK=32, 4 waves. M mult of 128, K mult of 32, N ragged.
// ---------------------------------------------------------------------------
#define LDST 40

template <int APK, int SPLITC>
__global__ __launch_bounds__(256) void gemm_bf3p(
    const unsigned short* __restrict__ Ah_g,
    const unsigned short* __restrict__ Al_g, int lda,
    const unsigned short* __restrict__ Bh_g,
    const unsigned short* __restrict__ Bl_g, int ldb,
    float* __restrict__ C0, float* __restrict__ C1, int ldc,
    int N, int K)
{
    __shared__ unsigned short Ah[128 * LDST], Al[128 * LDST];
    __shared__ unsigned short Bh[128 * LDST], Bl[128 * LDST];

    const int tid  = threadIdx.x;
    const int lane = tid & 63;
    const int wave = tid >> 6;
    const int bm   = blockIdx.y << 7;
    const int bn   = blockIdx.x << 7;

    // planar staging geometry: 2 sweeps x (64 rows x 8 cols) per plane
    const int sr = tid >> 2;          // 0..63
    const int sc = (tid & 3) << 3;    // 0,8,16,24

    // packed-A staging geometry: 4 sweeps x (32 rows x 4 elts)
    const int pr = tid >> 3;          // 0..31
    const int pc = (tid & 7) << 2;    // 0..28

    const int wm = (wave >> 1) << 6;
    const int wn = (wave & 1) << 6;
    const int fr = lane & 15;
    const int kg = lane >> 4;

    f32x4 acc[4][4];
#pragma unroll
    for (int i = 0; i < 4; ++i)
#pragma unroll
        for (int j = 0; j < 4; ++j)
            acc[i][j] = (f32x4){0.f, 0.f, 0.f, 0.f};

    const ushort8 zz = {0, 0, 0, 0, 0, 0, 0, 0};

    for (int k0 = 0; k0 < K; k0 += 32) {
        ushort8 a_h[2], a_l[2], b_h[2], b_l[2];
        ushort4 p_h[4], p_l[4];

        if (APK == 0) {
#pragma unroll
            for (int s = 0; s < 2; ++s) {
                size_t ao = (size_t)(bm + sr + s * 64) * lda + k0 + sc;
                a_h[s] = *(const ushort8*)&Ah_g[ao];
                a_l[s] = *(const ushort8*)&Al_g[ao];
            }
        } else {
            const unsigned* Apk = (const unsigned*)Ah_g;
#pragma unroll
            for (int s = 0; s < 4; ++s) {
                size_t ao = (size_t)(bm + pr + s * 32) * lda + k0 + pc;
                uint4 pk = *(const uint4*)&Apk[ao];
                p_h[s].x = (unsigned short)(pk.x >> 16);
                p_h[s].y = (unsigned short)(pk.y >> 16);
                p_h[s].z = (unsigned short)(pk.z >> 16);
                p_h[s].w = (unsigned short)(pk.w >> 16);
                p_l[s].x = (unsigned short)(pk.x & 0xffff);
                p_l[s].y = (unsigned short)(pk.y & 0xffff);
                p_l[s].z = (unsigned short)(pk.z & 0xffff);
                p_l[s].w = (unsigned short)(pk.w & 0xffff);
            }
        }
#pragma unroll
        for (int s = 0; s < 2; ++s) {
            int r = bn + sr + s * 64;
            if (r < N) {
                size_t bo = (size_t)r * ldb + k0 + sc;
                b_h[s] = *(const ushort8*)&Bh_g[bo];
                b_l[s] = *(const ushort8*)&Bl_g[bo];
            } else {
                b_h[s] = zz; b_l[s] = zz;
            }
        }

        __syncthreads();   // previous iteration's frag reads complete
        if (APK == 0) {
#pragma unroll
            for (int s = 0; s < 2; ++s) {
                const int o = (sr + s * 64) * LDST + sc;
                *(ushort8*)&Ah[o] = a_h[s];
                *(ushort8*)&Al[o] = a_l[s];
            }
        } else {
#pragma unroll
            for (int s = 0; s < 4; ++s) {
                const int o = (pr + s * 32) * LDST + pc;
                *(ushort4*)&Ah[o] = p_h[s];
                *(ushort4*)&Al[o] = p_l[s];
            }
        }
#pragma unroll
        for (int s = 0; s < 2; ++s) {
            const int o = (sr + s * 64) * LDST + sc;
            *(ushort8*)&Bh[o] = b_h[s];
            *(ushort8*)&Bl[o] = b_l[s];
        }
        __syncthreads();

        bf16x8 fa_h[4], fa_l[4], fb_h[4], fb_l[4];
#pragma unroll
        for (int f = 0; f < 4; ++f) {
            const int ra = (wm + f * 16 + fr) * LDST + (kg << 3);
            const int rb = (wn + f * 16 + fr) * LDST + (kg << 3);
            fa_h[f] = *(const bf16x8*)&Ah[ra];
            fa_l[f] = *(const bf16x8*)&Al[ra];
            fb_h[f] = *(const bf16x8*)&Bh[rb];
            fb_l[f] = *(const bf16x8*)&Bl[rb];
        }

#pragma unroll
        for (int i = 0; i < 4; ++i)
#pragma unroll
            for (int j = 0; j < 4; ++j) {
                acc[i][j] = __builtin_amdgcn_mfma_f32_16x16x32_bf16(
                    fa_h[i], fb_h[j], acc[i][j], 0, 0, 0);
                acc[i][j] = __builtin_amdgcn_mfma_f32_16x16x32_bf16(
                    fa_l[i], fb_h[j], acc[i][j], 0, 0, 0);
                acc[i][j] = __builtin_amdgcn_mfma_f32_16x16x32_bf16(
                    fa_h[i], fb_l[j], acc[i][j], 0, 0, 0);
            }
    }

    // epilogue: D col = lane&15, row = (lane>>4)*4 + reg
    const int erow = (lane >> 4) << 2;
    const int ecol = lane & 15;
    float* Cw = C0;
    int cb = bn;
    if (SPLITC && bn >= DINNER) { Cw = C1; cb = bn - DINNER; }
#pragma unroll
    for (int i = 0; i < 4; ++i) {
        const int row0 = bm + wm + i * 16 + erow;
#pragma unroll
        for (int j = 0; j < 4; ++j) {
            const int col = wn + j * 16 + ecol;
            if (bn + col < N) {
#pragma unroll
                for (int r = 0; r < 4; ++r)
                    Cw[(size_t)(row0 + r) * ldc + cb + col] = acc[i][j][r];
            }
        }
    }
}

// ---------------------------------------------------------------------------
// fp32 NT GEMM with softplus(acc + bias[n]) epilogue (delta GEMM, K=64).
// ---------------------------------------------------------------------------
__global__ __launch_bounds__(256) void gemm_nt_sp(
    const float* __restrict__ A, int lda,
    const float* __restrict__ B, int ldb,
    const float* __restrict__ bias,
    float* __restrict__ C, int ldc,
    int N, int K)
{
    __shared__ float As[16][64];
    __shared__ float Bs[16][64];

    const int tid  = threadIdx.x;
    const int tx   = tid & 15;
    const int ty   = tid >> 4;
    const int bm   = blockIdx.y << 6;
    const int bn   = blockIdx.x << 6;
    const int lrow = tid >> 2;
    const int lcol = (tid & 3) << 2;

    const float* Aptr = A + (size_t)(bm + lrow) * lda + lcol;
    const float* Bptr = B + (size_t)(bn + lrow) * ldb + lcol;
    const bool   bval = (bn + lrow) < N;

    float acc[4][4] = {};

    for (int k0 = 0; k0 < K; k0 += 16) {
        float4 av = *(const float4*)(Aptr + k0);
        float4 bv = make_float4(0.f, 0.f, 0.f, 0.f);
        if (bval) bv = *(const float4*)(Bptr + k0);

        __syncthreads();
        As[lcol + 0][lrow] = av.x;
        As[lcol + 1][lrow] = av.y;
        As[lcol + 2][lrow] = av.z;
        As[lcol + 3][lrow] = av.w;
        Bs[lcol + 0][lrow] = bv.x;
        Bs[lcol + 1][lrow] = bv.y;
        Bs[lcol + 2][lrow] = bv.z;
        Bs[lcol + 3][lrow] = bv.w;
        __syncthreads();

#pragma unroll
        for (int kk = 0; kk < 16; ++kk) {
            float4 a4 = *(const float4*)&As[kk][ty << 2];
            float4 b4 = *(const float4*)&Bs[kk][tx << 2];
            float ar[4] = {a4.x, a4.y, a4.z, a4.w};
            float br[4] = {b4.x, b4.y, b4.z, b4.w};
#pragma unroll
            for (int i = 0; i < 4; ++i)
#pragma unroll
                for (int j = 0; j < 4; ++j)
                    acc[i][j] = fmaf(ar[i], br[j], acc[i][j]);
        }
    }

    const int cm = bm + (ty << 2);
    const int cn = bn + (tx << 2);
#pragma unroll
    for (int i = 0; i < 4; ++i) {
#pragma unroll
        for (int j = 0; j < 4; ++j) {
            int nn = cn + j;
            if (nn < N) {
                float v = acc[i][j] + bias[nn];
                v = (v > 20.f) ? v : log1pf(expf(v));
                C[(size_t)(cm + i) * ldc + nn] = v;
            }
        }
    }
}

// ---------------------------------------------------------------------------
// A_eff[d][n] = -exp(A_log[d][n]) + scale * (U[d,:] @ V[:,n]) / sqrt(8)
// ---------------------------------------------------------------------------
__global__ __launch_bounds__(256) void a_eff_kernel(
    const float* __restrict__ A_log, const float* __restrict__ U,
    const float* __restrict__ V, const float* __restrict__ scale_p,
    float* __restrict__ Aeff)
{
    int d = blockIdx.x * 256 + threadIdx.x;
    if (d >= DINNER) return;
    const float s = (*scale_p) * 0.35355339059327378f;  // 1/sqrt(8)
    float ur[8];
#pragma unroll
    for (int r = 0; r < 8; ++r) ur[r] = U[d * 8 + r];
#pragma unroll
    for (int n = 0; n < DSTATE; ++n) {
        float acc = 0.f;
#pragma unroll
        for (int r = 0; r < 8; ++r) acc = fmaf(ur[r], V[r * 8 + n], acc);
        Aeff[d * 8 + n] = -expf(A_log[d * 8 + n]) + s * acc;
    }
}

// ---------------------------------------------------------------------------
// Depthwise causal conv (D_CONV=4) + bias + SiLU; emits planar hi/lo bf16.
// ---------------------------------------------------------------------------
__global__ __launch_bounds__(256) void conv_silu_kernel(
    const float* __restrict__ xbuf, const float* __restrict__ cw,
    const float* __restrict__ cb,
    unsigned short* __restrict__ xth, unsigned short* __restrict__ xtl)
{
    const int d = blockIdx.x * 256 + threadIdx.x;
    const int l = blockIdx.y;
    const int b = blockIdx.z;

    float4 w = *(const float4*)&cw[d * 4];
    size_t idx = ((size_t)b * SEQLEN + l) * DINNER + d;

    float acc = cb[d];
    if (l >= 3) acc = fmaf(w.x, xbuf[idx - 3 * (size_t)DINNER], acc);
    if (l >= 2) acc = fmaf(w.y, xbuf[idx - 2 * (size_t)DINNER], acc);
    if (l >= 1) acc = fmaf(w.z, xbuf[idx - 1 * (size_t)DINNER], acc);
    acc = fmaf(w.w, xbuf[idx], acc);

    float sig = 1.f / (1.f + expf(-acc));
    float v = acc * sig;
    unsigned short h = f2bf(v);
    xth[idx] = h;
    xtl[idx] = f2bf(v - bf2f(h));
}

// ---------------------------------------------------------------------------
// Scan phase 1: per-chunk (P, S), streaming delta + planar u.
// ---------------------------------------------------------------------------
__global__ __launch_bounds__(256) void scan_phase1(
    const float* __restrict__ delta,       // xbuf, stride DINNER
    const unsigned short* __restrict__ uh,
    const unsigned short* __restrict__ ul,
    const float* __restrict__ xdbl,
    const float* __restrict__ Aeff,
    float* __restrict__ P, float* __restrict__ S)
{
    const int tid  = threadIdx.x;
    const int lane = tid & 63;
    const int wave = tid >> 6;
    const int n    = lane & 7;
    const int d    = blockIdx.x * 32 + wave * 8 + (lane >> 3);
    const int c    = blockIdx.y;
    const int b    = blockIdx.z;

    const float a = Aeff[d * 8 + n];

    const size_t t0 = (size_t)c * CHUNK;
    size_t rowD = ((size_t)b * SEQLEN + t0) * DINNER + d;
    size_t rowX = ((size_t)b * SEQLEN + t0) * NK;

    float Ss = 0.f, sdl = 0.f;
    for (int t = 0; t < CHUNK; ++t) {
        float dl = delta[rowD];
        float ut = bf2f(uh[rowD]) + bf2f(ul[rowD]);
        float Bn = xdbl[rowX + DTRANK + n];

        float dA = expf(dl * a);
        Ss = fmaf(Ss, dA, (dl * ut) * Bn);
        sdl += dl;
        rowD += DINNER; rowX += NK;
    }
    size_t idx = (((size_t)b * NCHUNK + c) * DINNER + d) * 8 + n;
    P[idx] = expf(sdl * a);
    S[idx] = Ss;
}

// ---------------------------------------------------------------------------
// Scan combine: sequential over 16 chunks per (b,d,n). P <- H0 in place.
// ---------------------------------------------------------------------------
__global__ __launch_bounds__(256) void scan_combine(
    float* __restrict__ P, const float* __restrict__ S)
{
    const int i = blockIdx.x * 256 + threadIdx.x;
    if (i >= BATCH * DINNER * DSTATE) return;
    const int b  = i / (DINNER * DSTATE);
    const int dn = i - b * (DINNER * DSTATE);

    float running = 0.f;
#pragma unroll
    for (int c = 0; c < NCHUNK; ++c) {
        size_t idx = (size_t)(b * NCHUNK + c) * (DINNER * DSTATE) + dn;
        float Pc = P[idx];
        float Sc = S[idx];
        P[idx] = running;
        running = fmaf(running, Pc, Sc);
    }
}

// ---------------------------------------------------------------------------
// Scan phase 2: recurrence from H0; y overwrites delta in place as PACKED
// split-bf16 (hi<<16 | lo) for the out_proj GEMM's APK=1 path.
// ---------------------------------------------------------------------------
__global__ __launch_bounds__(256) void scan_phase2(
    float* __restrict__ deltay,            // xbuf: delta read / packed y write
    const unsigned short* __restrict__ uh,
    const unsigned short* __restrict__ ul,
    const float* __restrict__ xdbl,
    const float* __restrict__ zbuf,        // stride DINNER
    const float* __restrict__ Aeff,
    const float* __restrict__ Dvec,
    const float* __restrict__ H0)
{
    const int tid  = threadIdx.x;
    const int lane = tid & 63;
    const int wave = tid >> 6;
    const int n    = lane & 7;
    const int d    = blockIdx.x * 32 + wave * 8 + (lane >> 3);
    const int c    = blockIdx.y;
    const int b    = blockIdx.z;

    const float a  = Aeff[d * 8 + n];
    const float Dd = Dvec[d];

    float h = H0[(((size_t)b * NCHUNK + c) * DINNER + d) * 8 + n];

    const size_t t0 = (size_t)c * CHUNK;
    size_t rowD = ((size_t)b * SEQLEN + t0) * DINNER + d;
    size_t rowX = ((size_t)b * SEQLEN + t0) * NK;

    for (int t = 0; t < CHUNK; ++t) {
        float dl = deltay[rowD];
        float ut = bf2f(uh[rowD]) + bf2f(ul[rowD]);
        float zt = zbuf[rowD];
        float Bn = xdbl[rowX + DTRANK + n];
        float Cn = xdbl[rowX + DTRANK + DSTATE + n];

        float dA = expf(dl * a);
        h = fmaf(h, dA, (dl * ut) * Bn);

        float p = h * Cn;
        p += __shfl_xor(p, 1);
        p += __shfl_xor(p, 2);
        p += __shfl_xor(p, 4);

        if (n == 0) {
            float sig = 1.f / (1.f + expf(-zt));
            float yv = (p + ut * Dd) * (zt * sig);
            unsigned short yh = f2bf(yv);
            unsigned short yl = f2bf(yv - bf2f(yh));
            ((unsigned*)deltay)[rowD] = ((unsigned)yh << 16) | yl;
        }
        rowD += DINNER; rowX += NK;
    }
}

// ---------------------------------------------------------------------------
// Launch
// ---------------------------------------------------------------------------
extern "C" void kernel_launch(void* const* d_in, const int* in_sizes, int n_in,
                              void* d_out, int out_size, void* d_ws, size_t ws_size,
                              hipStream_t stream)
{
    const float* hidden     = (const float*)d_in[0];
    const float* in_proj_w  = (const float*)d_in[1];
    const float* conv_w     = (const float*)d_in[2];
    const float* conv_b     = (const float*)d_in[3];
    const float* x_proj_w   = (const float*)d_in[4];
    const float* dt_proj_w  = (const float*)d_in[5];
    const float* dt_proj_b  = (const float*)d_in[6];
    const float* A_log      = (const float*)d_in[7];
    const float* Dvec       = (const float*)d_in[8];
    const float* out_proj_w = (const float*)d_in[9];
    const float* U_param    = (const float*)d_in[10];
    const float* V_param    = (const float*)d_in[11];
    const float* scale_p    = (const float*)d_in[12];
    float* out = (float*)d_out;

    // ---- d_ws layout (192 MiB) ----
    float* xbuf = (float*)d_ws;                              // BL*2048 f32
    float* zbuf = xbuf + (size_t)BL * DINNER;                // BL*2048 f32
    unsigned short* xth = (unsigned short*)(zbuf + (size_t)BL * DINNER);
    unsigned short* xtl = xth + (size_t)BL * DINNER;

    // in_proj_w splits live in the xt region until the conv overwrites it
    unsigned short* ipwh = xth;
    unsigned short* ipwl = xth + (size_t)E2 * DMODEL;        // 4.19M ushorts

    // ---- d_out scratch ----
    // phase A (GEMM1): hidden splits occupy all of d_out
    unsigned short* hidh = (unsigned short*)out;
    unsigned short* hidl = hidh + (size_t)BL * DMODEL;
    // phase B (after GEMM1):
    float* xdbl = out;                                        //   655,360 f
    float* Aeff = xdbl + (size_t)BL * NK;                     //    16,384 f
    float* Parr = Aeff + (size_t)DINNER * DSTATE;             //   524,288 f
    float* Sarr = Parr + (size_t)BATCH * NCHUNK * DINNER * DSTATE;
    unsigned short* xpwh = (unsigned short*)(Sarr + (size_t)BATCH * NCHUNK * DINNER * DSTATE);
    unsigned short* xpwl = xpwh + (size_t)NK * DINNER;

    // out_proj_w splits reuse zbuf once z is consumed (after phase2)
    unsigned short* opwh = (unsigned short*)zbuf;
    unsigned short* opwl = opwh + (size_t)DMODEL * DINNER;

    // 0) pre-splits needed by GEMM1
    split_kernel<<<dim3(BL * DMODEL / 1024), 256, 0, stream>>>(
        hidden, hidh, hidl, BL * DMODEL / 4);
    split_kernel<<<dim3(E2 * DMODEL / 1024), 256, 0, stream>>>(
        in_proj_w, ipwh, ipwl, E2 * DMODEL / 4);

    // 1) [xbuf|zbuf] = hidden @ in_proj_w^T   (8192 x 4096, K=1024) [MFMA]
    gemm_bf3p<0, 1><<<dim3(E2 / 128, BL / 128), 256, 0, stream>>>(
        hidh, hidl, DMODEL, ipwh, ipwl, DMODEL,
        xbuf, zbuf, DINNER, E2, DMODEL);

    // 2) A_eff + x_proj_w splits (d_out scratch now free)
    a_eff_kernel<<<dim3(DINNER / 256), 256, 0, stream>>>(
        A_log, U_param, V_param, scale_p, Aeff);
    split_kernel<<<dim3(NK * DINNER / 1024), 256, 0, stream>>>(
        x_proj_w, xpwh, xpwl, NK * DINNER / 4);

    // 3) depthwise conv + silu -> planar xt (overwrites in_proj_w splits)
    conv_silu_kernel<<<dim3(DINNER / 256, SEQLEN, BATCH), 256, 0, stream>>>(
        xbuf, conv_w, conv_b, xth, xtl);

    // 4) x_dbl = xt @ x_proj_w^T   (8192 x 80, K=2048) [MFMA]
    gemm_bf3p<0, 0><<<dim3(1, BL / 128), 256, 0, stream>>>(
        xth, xtl, DINNER, xpwh, xpwl, DINNER,
        xdbl, nullptr, NK, NK, DINNER);

    // 5) delta = softplus(dt_lr @ dt_proj_w^T + b) -> xbuf (fp32, K=64)
    gemm_nt_sp<<<dim3(DINNER / 64, BL / 64), 256, 0, stream>>>(
        xdbl, NK, dt_proj_w, DTRANK, dt_proj_b, xbuf, DINNER, DINNER, DTRANK);

    // 6) chunked selective scan; phase2 packs y over delta in place
    scan_phase1<<<dim3(DINNER / 32, NCHUNK, BATCH), 256, 0, stream>>>(
        xbuf, xth, xtl, xdbl, Aeff, Parr, Sarr);
    scan_combine<<<dim3((BATCH * DINNER * DSTATE + 255) / 256), 256, 0, stream>>>(
        Parr, Sarr);
    scan_phase2<<<dim3(DINNER / 32, NCHUNK, BATCH), 256, 0, stream>>>(
        xbuf, xth, xtl, xdbl, zbuf, Aeff, Dvec, Parr);

    // 7) out_proj_w splits into zbuf (z consumed), then final GEMM
    split_kernel<<<dim3(DMODEL * DINNER / 1024), 256, 0, stream>>>(
        out_proj_w, opwh, opwl, DMODEL * DINNER / 4);

    // 8) out = y @ out_proj_w^T   (8192 x 1024, K=2048) [MFMA, packed A]
    gemm_bf3p<1, 0><<<dim3(DMODEL / 128, BL / 128), 256, 0, stream>>>(
        (const unsigned short*)xbuf, nullptr, DINNER, opwh, opwl, DINNER,
        out, nullptr, DMODEL, DMODEL, DINNER);
}

// Round 8
// 721.239 us; speedup vs baseline: 7.1011x; 1.3770x over previous
//
#include <hip/hip_runtime.h>
#include <hip/hip_bf16.h>
#include <math.h>

// ---------------------------------------------------------------------------
// Mamba forward. Planar split-bf16 (3-pass) MFMA GEMMs with PRE-SPLIT
// operands, fp32 GEMM w/ softplus epilogue for delta, chunked 3-phase
// selective scan with THREAD-PER-D layout (8 n-states in registers,
// no shuffles, no divergence, v_exp_f32 with prefolded log2e).
// Shapes: B=2, L=4096, D_MODEL=1024, D_INNER=2048, E2=4096, D_STATE=8,
//         D_CONV=4, DT_RANK=64, NK=80, R_RANK=8.
//
// d_ws (192 MiB): xbuf (BL,2048) fp32  [x -> conv -> dead -> delta -> y(pk)]
//                 zbuf (BL,2048) fp32  [z; after phase2: out_proj_w splits]
//                 xth/xtl (BL,2048) ushort planes  [in_proj_w splits first,
//                                                   then u hi/lo from conv]
// d_out scratch: hidden hi/lo splits (GEMM1), then xdbl/Aeff2/P/S/xpw splits.
// ---------------------------------------------------------------------------

#define BATCH   2
#define SEQLEN  4096
#define DMODEL  1024
#define DINNER  2048
#define E2      4096
#define DSTATE  8
#define DTRANK  64
#define NK      80
#define BL      (BATCH * SEQLEN)
#define CHUNK   64
#define NCHUNK  (SEQLEN / CHUNK)   // 64
#define LOG2E   1.44269504088896341f

typedef short bf16x8 __attribute__((ext_vector_type(8)));
typedef float f32x4  __attribute__((ext_vector_type(4)));
typedef unsigned short ushort8 __attribute__((ext_vector_type(8)));

__device__ __forceinline__ unsigned short f2bf(float f) {
    unsigned u = __float_as_uint(f);
    u += 0x7FFF + ((u >> 16) & 1);
    return (unsigned short)(u >> 16);
}
__device__ __forceinline__ float bf2f(unsigned short h) {
    return __uint_as_float((unsigned)h << 16);
}
// 2^x via the hardware transcendental (1-ulp; args here are well in range)
__device__ __forceinline__ float fexp2(float x) {
    float r;
    asm("v_exp_f32 %0, %1" : "=v"(r) : "v"(x));
    return r;
}
__device__ __forceinline__ float frcp(float x) {
    float r;
    asm("v_rcp_f32 %0, %1" : "=v"(r) : "v"(x));
    return r;
}

// ---------------------------------------------------------------------------
// Elementwise fp32 -> planar (hi, lo) bf16 split. n4 = n/4 float4 groups.
// ---------------------------------------------------------------------------
__global__ __launch_bounds__(256) void split_kernel(
    const float* __restrict__ src,
    unsigned short* __restrict__ hi, unsigned short* __restrict__ lo, int n4)
{
    int i = blockIdx.x * 256 + threadIdx.x;
    if (i >= n4) return;
    float4 v = ((const float4*)src)[i];
    ushort4 h, l;
    h.x = f2bf(v.x); h.y = f2bf(v.y); h.z = f2bf(v.z); h.w = f2bf(v.w);
    l.x = f2bf(v.x - bf2f(h.x)); l.y = f2bf(v.y - bf2f(h.y));
    l.z = f2bf(v.z - bf2f(h.z)); l.w = f2bf(v.w - bf2f(h.w));
    ((ushort4*)hi)[i] = h;
    ((ushort4*)lo)[i] = l;
}

// ---------------------------------------------------------------------------
// Planar split-bf16 3-pass MFMA NT GEMM. C = A * B^T, fp32 accumulate.
// APK=0: planar hi/lo A. APK=1: packed uint (hi<<16|lo) A.
// SPLITC=1: N-split C store. 128x128 tile, BK=32, 4 waves.
// ---------------------------------------------------------------------------
#define LDST 40

template <int APK, int SPLITC>
__global__ __launch_bounds__(256) void gemm_bf3p(
    const unsigned short* __restrict__ Ah_g,
    const unsigned short* __restrict__ Al_g, int lda,
    const unsigned short* __restrict__ Bh_g,
    const unsigned short* __restrict__ Bl_g, int ldb,
    float* __restrict__ C0, float* __restrict__ C1, int ldc,
    int N, int K)
{
    __shared__ unsigned short Ah[128 * LDST], Al[128 * LDST];
    __shared__ unsigned short Bh[128 * LDST], Bl[128 * LDST];

    const int tid  = threadIdx.x;
    const int lane = tid & 63;
    const int wave = tid >> 6;
    const int bm   = blockIdx.y << 7;
    const int bn   = blockIdx.x << 7;

    const int sr = tid >> 2;          // 0..63
    const int sc = (tid & 3) << 3;    // 0,8,16,24

    const int pr = tid >> 3;          // 0..31
    const int pc = (tid & 7) << 2;    // 0..28

    const int wm = (wave >> 1) << 6;
    const int wn = (wave & 1) << 6;
    const int fr = lane & 15;
    const int kg = lane >> 4;

    f32x4 acc[4][4];
#pragma unroll
    for (int i = 0; i < 4; ++i)
#pragma unroll
        for (int j = 0; j < 4; ++j)
            acc[i][j] = (f32x4){0.f, 0.f, 0.f, 0.f};

    const ushort8 zz = {0, 0, 0, 0, 0, 0, 0, 0};

    for (int k0 = 0; k0 < K; k0 += 32) {
        ushort8 a_h[2], a_l[2], b_h[2], b_l[2];
        ushort4 p_h[4], p_l[4];

        if (APK == 0) {
#pragma unroll
            for (int s = 0; s < 2; ++s) {
                size_t ao = (size_t)(bm + sr + s * 64) * lda + k0 + sc;
                a_h[s] = *(const ushort8*)&Ah_g[ao];
                a_l[s] = *(const ushort8*)&Al_g[ao];
            }
        } else {
            const unsigned* Apk = (const unsigned*)Ah_g;
#pragma unroll
            for (int s = 0; s < 4; ++s) {
                size_t ao = (size_t)(bm + pr + s * 32) * lda + k0 + pc;
                uint4 pk = *(const uint4*)&Apk[ao];
                p_h[s].x = (unsigned short)(pk.x >> 16);
                p_h[s].y = (unsigned short)(pk.y >> 16);
                p_h[s].z = (unsigned short)(pk.z >> 16);
                p_h[s].w = (unsigned short)(pk.w >> 16);
                p_l[s].x = (unsigned short)(pk.x & 0xffff);
                p_l[s].y = (unsigned short)(pk.y & 0xffff);
                p_l[s].z = (unsigned short)(pk.z & 0xffff);
                p_l[s].w = (unsigned short)(pk.w & 0xffff);
            }
        }
#pragma unroll
        for (int s = 0; s < 2; ++s) {
            int r = bn + sr + s * 64;
            if (r < N) {
                size_t bo = (size_t)r * ldb + k0 + sc;
                b_h[s] = *(const ushort8*)&Bh_g[bo];
                b_l[s] = *(const ushort8*)&Bl_g[bo];
            } else {
                b_h[s] = zz; b_l[s] = zz;
            }
        }

        __syncthreads();
        if (APK == 0) {
#pragma unroll
            for (int s = 0; s < 2; ++s) {
                const int o = (sr + s * 64) * LDST + sc;
                *(ushort8*)&Ah[o] = a_h[s];
                *(ushort8*)&Al[o] = a_l[s];
            }
        } else {
#pragma unroll
            for (int s = 0; s < 4; ++s) {
                const int o = (pr + s * 32) * LDST + pc;
                *(ushort4*)&Ah[o] = p_h[s];
                *(ushort4*)&Al[o] = p_l[s];
            }
        }
#pragma unroll
        for (int s = 0; s < 2; ++s) {
            const int o = (sr + s * 64) * LDST + sc;
            *(ushort8*)&Bh[o] = b_h[s];
            *(ushort8*)&Bl[o] = b_l[s];
        }
        __syncthreads();

        bf16x8 fa_h[4], fa_l[4], fb_h[4], fb_l[4];
#pragma unroll
        for (int f = 0; f < 4; ++f) {
            const int ra = (wm + f * 16 + fr) * LDST + (kg << 3);
            const int rb = (wn + f * 16 + fr) * LDST + (kg << 3);
            fa_h[f] = *(const bf16x8*)&Ah[ra];
            fa_l[f] = *(const bf16x8*)&Al[ra];
            fb_h[f] = *(const bf16x8*)&Bh[rb];
            fb_l[f] = *(const bf16x8*)&Bl[rb];
        }

#pragma unroll
        for (int i = 0; i < 4; ++i)
#pragma unroll
            for (int j = 0; j < 4; ++j) {
                acc[i][j] = __builtin_amdgcn_mfma_f32_16x16x32_bf16(
                    fa_h[i], fb_h[j], acc[i][j], 0, 0, 0);
                acc[i][j] = __builtin_amdgcn_mfma_f32_16x16x32_bf16(
                    fa_l[i], fb_h[j], acc[i][j], 0, 0, 0);
                acc[i][j] = __builtin_amdgcn_mfma_f32_16x16x32_bf16(
                    fa_h[i], fb_l[j], acc[i][j], 0, 0, 0);
            }
    }

    const int erow = (lane >> 4) << 2;
    const int ecol = lane & 15;
    float* Cw = C0;
    int cb = bn;
    if (SPLITC && bn >= DINNER) { Cw = C1; cb = bn - DINNER; }
#pragma unroll
    for (int i = 0; i < 4; ++i) {
        const int row0 = bm + wm + i * 16 + erow;
#pragma unroll
        for (int j = 0; j < 4; ++j) {
            const int col = wn + j * 16 + ecol;
            if (bn + col < N) {
#pragma unroll
                for (int r = 0; r < 4; ++r)
                    Cw[(size_t)(row0 + r) * ldc + cb + col] = acc[i][j][r];
            }
        }
    }
}

// ---------------------------------------------------------------------------
// fp32 NT GEMM with softplus(acc + bias[n]) epilogue (delta GEMM, K=64).
// ---------------------------------------------------------------------------
__global__ __launch_bounds__(256) void gemm_nt_sp(
    const float* __restrict__ A, int lda,
    const float* __restrict__ B, int ldb,
    const float* __restrict__ bias,
    float* __restrict__ C, int ldc,
    int N, int K)
{
    __shared__ float As[16][64];
    __shared__ float Bs[16][64];

    const int tid  = threadIdx.x;
    const int tx   = tid & 15;
    const int ty   = tid >> 4;
    const int bm   = blockIdx.y << 6;
    const int bn   = blockIdx.x << 6;
    const int lrow = tid >> 2;
    const int lcol = (tid & 3) << 2;

    const float* Aptr = A + (size_t)(bm + lrow) * lda + lcol;
    const float* Bptr = B + (size_t)(bn + lrow) * ldb + lcol;
    const bool   bval = (bn + lrow) < N;

    float acc[4][4] = {};

    for (int k0 = 0; k0 < K; k0 += 16) {
        float4 av = *(const float4*)(Aptr + k0);
        float4 bv = make_float4(0.f, 0.f, 0.f, 0.f);
        if (bval) bv = *(const float4*)(Bptr + k0);

        __syncthreads();
        As[lcol + 0][lrow] = av.x;
        As[lcol + 1][lrow] = av.y;
        As[lcol + 2][lrow] = av.z;
        As[lcol + 3][lrow] = av.w;
        Bs[lcol + 0][lrow] = bv.x;
        Bs[lcol + 1][lrow] = bv.y;
        Bs[lcol + 2][lrow] = bv.z;
        Bs[lcol + 3][lrow] = bv.w;
        __syncthreads();

#pragma unroll
        for (int kk = 0; kk < 16; ++kk) {
            float4 a4 = *(const float4*)&As[kk][ty << 2];
            float4 b4 = *(const float4*)&Bs[kk][tx << 2];
            float ar[4] = {a4.x, a4.y, a4.z, a4.w};
            float br[4] = {b4.x, b4.y, b4.z, b4.w};
#pragma unroll
            for (int i = 0; i < 4; ++i)
#pragma unroll
                for (int j = 0; j < 4; ++j)
                    acc[i][j] = fmaf(ar[i], br[j], acc[i][j]);
        }
    }

    const int cm = bm + (ty << 2);
    const int cn = bn + (tx << 2);
#pragma unroll
    for (int i = 0; i < 4; ++i) {
#pragma unroll
        for (int j = 0; j < 4; ++j) {
            int nn = cn + j;
            if (nn < N) {
                float v = acc[i][j] + bias[nn];
                v = (v > 20.f) ? v : log1pf(expf(v));
                C[(size_t)(cm + i) * ldc + nn] = v;
            }
        }
    }
}

// ---------------------------------------------------------------------------
// A_eff2[d][n] = (-exp(A_log) + scale*(U@V)/sqrt(8)) * log2(e)
// (prefolded for v_exp_f32 use in the scan)
// ---------------------------------------------------------------------------
__global__ __launch_bounds__(256) void a_eff_kernel(
    const float* __restrict__ A_log, const float* __restrict__ U,
    const float* __restrict__ V, const float* __restrict__ scale_p,
    float* __restrict__ Aeff2)
{
    int d = blockIdx.x * 256 + threadIdx.x;
    if (d >= DINNER) return;
    const float s = (*scale_p) * 0.35355339059327378f;  // 1/sqrt(8)
    float ur[8];
#pragma unroll
    for (int r = 0; r < 8; ++r) ur[r] = U[d * 8 + r];
#pragma unroll
    for (int n = 0; n < DSTATE; ++n) {
        float acc = 0.f;
#pragma unroll
        for (int r = 0; r < 8; ++r) acc = fmaf(ur[r], V[r * 8 + n], acc);
        Aeff2[d * 8 + n] = (-expf(A_log[d * 8 + n]) + s * acc) * LOG2E;
    }
}

// ---------------------------------------------------------------------------
// Depthwise causal conv (D_CONV=4) + bias + SiLU; emits planar hi/lo bf16.
// ---------------------------------------------------------------------------
__global__ __launch_bounds__(256) void conv_silu_kernel(
    const float* __restrict__ xbuf, const float* __restrict__ cw,
    const float* __restrict__ cb,
    unsigned short* __restrict__ xth, unsigned short* __restrict__ xtl)
{
    const int d = blockIdx.x * 256 + threadIdx.x;
    const int l = blockIdx.y;
    const int b = blockIdx.z;

    float4 w = *(const float4*)&cw[d * 4];
    size_t idx = ((size_t)b * SEQLEN + l) * DINNER + d;

    float acc = cb[d];
    if (l >= 3) acc = fmaf(w.x, xbuf[idx - 3 * (size_t)DINNER], acc);
    if (l >= 2) acc = fmaf(w.y, xbuf[idx - 2 * (size_t)DINNER], acc);
    if (l >= 1) acc = fmaf(w.z, xbuf[idx - 1 * (size_t)DINNER], acc);
    acc = fmaf(w.w, xbuf[idx], acc);

    float sig = 1.f / (1.f + expf(-acc));
    float v = acc * sig;
    unsigned short h = f2bf(v);
    xth[idx] = h;
    xtl[idx] = f2bf(v - bf2f(h));
}

// ---------------------------------------------------------------------------
// Scan phase 1 (thread-per-d): per-chunk (P, S). 8 n-states in registers.
// grid = (DINNER/256, NCHUNK, BATCH), block = 256.
// ---------------------------------------------------------------------------
__global__ __launch_bounds__(256) void scan_phase1(
    const float* __restrict__ delta,       // xbuf, stride DINNER
    const unsigned short* __restrict__ uh,
    const unsigned short* __restrict__ ul,
    const float* __restrict__ xdbl,        // (B*L, 80)
    const float* __restrict__ Aeff2,       // (2048, 8), * log2e
    float* __restrict__ P, float* __restrict__ S)
{
    const int d = blockIdx.x * 256 + threadIdx.x;
    const int c = blockIdx.y;
    const int b = blockIdx.z;

    const float4 a0 = *(const float4*)&Aeff2[d * 8];
    const float4 a1 = *(const float4*)&Aeff2[d * 8 + 4];

    float4 s0 = make_float4(0.f, 0.f, 0.f, 0.f);
    float4 s1 = make_float4(0.f, 0.f, 0.f, 0.f);
    float sdl = 0.f;

    size_t rowD = ((size_t)b * SEQLEN + (size_t)c * CHUNK) * DINNER + d;
    size_t rowX = ((size_t)b * SEQLEN + (size_t)c * CHUNK) * NK + DTRANK;

    for (int t = 0; t < CHUNK; ++t) {
        float dl = delta[rowD];
        float ut = bf2f(uh[rowD]) + bf2f(ul[rowD]);
        float4 B0 = *(const float4*)&xdbl[rowX];
        float4 B1 = *(const float4*)&xdbl[rowX + 4];
        float dlut = dl * ut;

        s0.x = fmaf(s0.x, fexp2(dl * a0.x), dlut * B0.x);
        s0.y = fmaf(s0.y, fexp2(dl * a0.y), dlut * B0.y);
        s0.z = fmaf(s0.z, fexp2(dl * a0.z), dlut * B0.z);
        s0.w = fmaf(s0.w, fexp2(dl * a0.w), dlut * B0.w);
        s1.x = fmaf(s1.x, fexp2(dl * a1.x), dlut * B1.x);
        s1.y = fmaf(s1.y, fexp2(dl * a1.y), dlut * B1.y);
        s1.z = fmaf(s1.z, fexp2(dl * a1.z), dlut * B1.z);
        s1.w = fmaf(s1.w, fexp2(dl * a1.w), dlut * B1.w);

        sdl += dl;
        rowD += DINNER; rowX += NK;
    }

    size_t idx = (((size_t)b * NCHUNK + c) * DINNER + d) * 8;
    float4 p0 = make_float4(fexp2(sdl * a0.x), fexp2(sdl * a0.y),
                            fexp2(sdl * a0.z), fexp2(sdl * a0.w));
    float4 p1 = make_float4(fexp2(sdl * a1.x), fexp2(sdl * a1.y),
                            fexp2(sdl * a1.z), fexp2(sdl * a1.w));
    *(float4*)&P[idx]     = p0;
    *(float4*)&P[idx + 4] = p1;
    *(float4*)&S[idx]     = s0;
    *(float4*)&S[idx + 4] = s1;
}

// ---------------------------------------------------------------------------
// Scan combine: sequential over NCHUNK chunks per (b,d,n). P <- H0 in place.
// ---------------------------------------------------------------------------
__global__ __launch_bounds__(256) void scan_combine(
    float* __restrict__ P, const float* __restrict__ S)
{
    const int i = blockIdx.x * 256 + threadIdx.x;
    if (i >= BATCH * DINNER * DSTATE) return;
    const int b  = i / (DINNER * DSTATE);
    const int dn = i - b * (DINNER * DSTATE);

    float running = 0.f;
    for (int c = 0; c < NCHUNK; ++c) {
        size_t idx = (size_t)(b * NCHUNK + c) * (DINNER * DSTATE) + dn;
        float Pc = P[idx];
        float Sc = S[idx];
        P[idx] = running;
        running = fmaf(running, Pc, Sc);
    }
}

// ---------------------------------------------------------------------------
// Scan phase 2 (thread-per-d): recurrence from H0; y overwrites delta in
// place as PACKED split-bf16 (hi<<16 | lo) for the out_proj APK=1 path.
// ---------------------------------------------------------------------------
__global__ __launch_bounds__(256) void scan_phase2(
    float* __restrict__ deltay,            // xbuf: delta read / packed y write
    const unsigned short* __restrict__ uh,
    const unsigned short* __restrict__ ul,
    const float* __restrict__ xdbl,
    const float* __restrict__ zbuf,        // stride DINNER
    const float* __restrict__ Aeff2,
    const float* __restrict__ Dvec,
    const float* __restrict__ H0)
{
    const int d = blockIdx.x * 256 + threadIdx.x;
    const int c = blockIdx.y;
    const int b = blockIdx.z;

    const float4 a0 = *(const float4*)&Aeff2[d * 8];
    const float4 a1 = *(const float4*)&Aeff2[d * 8 + 4];
    const float  Dd = Dvec[d];

    size_t hidx = (((size_t)b * NCHUNK + c) * DINNER + d) * 8;
    float4 h0 = *(const float4*)&H0[hidx];
    float4 h1 = *(const float4*)&H0[hidx + 4];

    size_t rowD = ((size_t)b * SEQLEN + (size_t)c * CHUNK) * DINNER + d;
    size_t rowX = ((size_t)b * SEQLEN + (size_t)c * CHUNK) * NK + DTRANK;

    for (int t = 0; t < CHUNK; ++t) {
        float dl = deltay[rowD];
        float ut = bf2f(uh[rowD]) + bf2f(ul[rowD]);
        float zt = zbuf[rowD];
        float4 B0 = *(const float4*)&xdbl[rowX];
        float4 B1 = *(const float4*)&xdbl[rowX + 4];
        float4 C0 = *(const float4*)&xdbl[rowX + 8];
        float4 C1 = *(const float4*)&xdbl[rowX + 12];
        float dlut = dl * ut;

        h0.x = fmaf(h0.x, fexp2(dl * a0.x), dlut * B0.x);
        h0.y = fmaf(h0.y, fexp2(dl * a0.y), dlut * B0.y);
        h0.z = fmaf(h0.z, fexp2(dl * a0.z), dlut * B0.z);
        h0.w = fmaf(h0.w, fexp2(dl * a0.w), dlut * B0.w);
        h1.x = fmaf(h1.x, fexp2(dl * a1.x), dlut * B1.x);
        h1.y = fmaf(h1.y, fexp2(dl * a1.y), dlut * B1.y);
        h1.z = fmaf(h1.z, fexp2(dl * a1.z), dlut * B1.z);
        h1.w = fmaf(h1.w, fexp2(dl * a1.w), dlut * B1.w);

        float p = h0.x * C0.x;
        p = fmaf(h0.y, C0.y, p);
        p = fmaf(h0.z, C0.z, p);
        p = fmaf(h0.w, C0.w, p);
        p = fmaf(h1.x, C1.x, p);
        p = fmaf(h1.y, C1.y, p);
        p = fmaf(h1.z, C1.z, p);
        p = fmaf(h1.w, C1.w, p);

        float sig = frcp(1.f + fexp2(-zt * LOG2E));
        float yv = (p + ut * Dd) * (zt * sig);
        unsigned short yhi = f2bf(yv);
        unsigned short ylo = f2bf(yv - bf2f(yhi));
        ((unsigned*)deltay)[rowD] = ((unsigned)yhi << 16) | ylo;

        rowD += DINNER; rowX += NK;
    }
}

// ---------------------------------------------------------------------------
// Launch
// ---------------------------------------------------------------------------
extern "C" void kernel_launch(void* const* d_in, const int* in_sizes, int n_in,
                              void* d_out, int out_size, void* d_ws, size_t ws_size,
                              hipStream_t stream)
{
    const float* hidden     = (const float*)d_in[0];
    const float* in_proj_w  = (const float*)d_in[1];
    const float* conv_w     = (const float*)d_in[2];
    const float* conv_b     = (const float*)d_in[3];
    const float* x_proj_w   = (const float*)d_in[4];
    const float* dt_proj_w  = (const float*)d_in[5];
    const float* dt_proj_b  = (const float*)d_in[6];
    const float* A_log      = (const float*)d_in[7];
    const float* Dvec       = (const float*)d_in[8];
    const float* out_proj_w = (const float*)d_in[9];
    const float* U_param    = (const float*)d_in[10];
    const float* V_param    = (const float*)d_in[11];
    const float* scale_p    = (const float*)d_in[12];
    float* out = (float*)d_out;

    // ---- d_ws layout (192 MiB) ----
    float* xbuf = (float*)d_ws;                              // BL*2048 f32
    float* zbuf = xbuf + (size_t)BL * DINNER;                // BL*2048 f32
    unsigned short* xth = (unsigned short*)(zbuf + (size_t)BL * DINNER);
    unsigned short* xtl = xth + (size_t)BL * DINNER;

    // in_proj_w splits live in the xt region until the conv overwrites it
    unsigned short* ipwh = xth;
    unsigned short* ipwl = xth + (size_t)E2 * DMODEL;

    // ---- d_out scratch ----
    unsigned short* hidh = (unsigned short*)out;
    unsigned short* hidl = hidh + (size_t)BL * DMODEL;
    float* xdbl = out;                                        //   655,360 f
    float* Aeff = xdbl + (size_t)BL * NK;                     //    16,384 f
    float* Parr = Aeff + (size_t)DINNER * DSTATE;             // 2,097,152 f
    float* Sarr = Parr + (size_t)BATCH * NCHUNK * DINNER * DSTATE;
    unsigned short* xpwh = (unsigned short*)(Sarr + (size_t)BATCH * NCHUNK * DINNER * DSTATE);
    unsigned short* xpwl = xpwh + (size_t)NK * DINNER;

    // out_proj_w splits reuse zbuf once z is consumed (after phase2)
    unsigned short* opwh = (unsigned short*)zbuf;
    unsigned short* opwl = opwh + (size_t)DMODEL * DINNER;

    // 0) pre-splits needed by GEMM1
    split_kernel<<<dim3(BL * DMODEL / 1024), 256, 0, stream>>>(
        hidden, hidh, hidl, BL * DMODEL / 4);
    split_kernel<<<dim3(E2 * DMODEL / 1024), 256, 0, stream>>>(
        in_proj_w, ipwh, ipwl, E2 * DMODEL / 4);

    // 1) [xbuf|zbuf] = hidden @ in_proj_w^T   (8192 x 4096, K=1024) [MFMA]
    gemm_bf3p<0, 1><<<dim3(E2 / 128, BL / 128), 256, 0, stream>>>(
        hidh, hidl, DMODEL, ipwh, ipwl, DMODEL,
        xbuf, zbuf, DINNER, E2, DMODEL);

    // 2) A_eff2 + x_proj_w splits (d_out scratch now free)
    a_eff_kernel<<<dim3(DINNER / 256), 256, 0, stream>>>(
        A_log, U_param, V_param, scale_p, Aeff);
    split_kernel<<<dim3(NK * DINNER / 1024), 256, 0, stream>>>(
        x_proj_w, xpwh, xpwl, NK * DINNER / 4);

    // 3) depthwise conv + silu -> planar xt (overwrites in_proj_w splits)
    conv_silu_kernel<<<dim3(DINNER / 256, SEQLEN, BATCH), 256, 0, stream>>>(
        xbuf, conv_w, conv_b, xth, xtl);

    // 4) x_dbl = xt @ x_proj_w^T   (8192 x 80, K=2048) [MFMA]
    gemm_bf3p<0, 0><<<dim3(1, BL / 128), 256, 0, stream>>>(
        xth, xtl, DINNER, xpwh, xpwl, DINNER,
        xdbl, nullptr, NK, NK, DINNER);

    // 5) delta = softplus(dt_lr @ dt_proj_w^T + b) -> xbuf (fp32, K=64)
    gemm_nt_sp<<<dim3(DINNER / 64, BL / 64), 256, 0, stream>>>(
        xdbl, NK, dt_proj_w, DTRANK, dt_proj_b, xbuf, DINNER, DINNER, DTRANK);

    // 6) chunked selective scan (thread-per-d); phase2 packs y in place
    scan_phase1<<<dim3(DINNER / 256, NCHUNK, BATCH), 256, 0, stream>>>(
        xbuf, xth, xtl, xdbl, Aeff, Parr, Sarr);
    scan_combine<<<dim3((BATCH * DINNER * DSTATE + 255) / 256), 256, 0, stream>>>(
        Parr, Sarr);
    scan_phase2<<<dim3(DINNER / 256, NCHUNK, BATCH), 256, 0, stream>>>(
        xbuf, xth, xtl, xdbl, zbuf, Aeff, Dvec, Parr);

    // 7) out_proj_w splits into zbuf (z consumed), then final GEMM
    split_kernel<<<dim3(DMODEL * DINNER / 1024), 256, 0, stream>>>(
        out_proj_w, opwh, opwl, DMODEL * DINNER / 4);

    // 8) out = y @ out_proj_w^T   (8192 x 1024, K=2048) [MFMA, packed A]
    gemm_bf3p<1, 0><<<dim3(DMODEL / 128, BL / 128), 256, 0, stream>>>(
        (const unsigned short*)xbuf, nullptr, DINNER, opwh, opwl, DINNER,
        out, nullptr, DMODEL, DMODEL, DINNER);
}

// Round 9
// 718.786 us; speedup vs baseline: 7.1253x; 1.0034x over previous
//
#include <hip/hip_runtime.h>
#include <hip/hip_bf16.h>
#include <math.h>

// ---------------------------------------------------------------------------
// Mamba forward. Planar split-bf16 (3-pass) MFMA GEMMs with PRE-SPLIT
// operands and XOR-SWIZZLED LDS (T2: unpadded 64B rows, bank-conflict-free
// b128 frag reads), fp32 GEMM w/ softplus epilogue for delta, chunked
// 3-phase selective scan with thread-per-d layout.
// Shapes: B=2, L=4096, D_MODEL=1024, D_INNER=2048, E2=4096, D_STATE=8,
//         D_CONV=4, DT_RANK=64, NK=80, R_RANK=8.
//
// d_ws (192 MiB): xbuf (BL,2048) fp32  [x -> conv -> dead -> delta -> y(pk)]
//                 zbuf (BL,2048) fp32  [z; after phase2: out_proj_w splits]
//                 xth/xtl (BL,2048) ushort planes  [in_proj_w splits first,
//                                                   then u hi/lo from conv]
// d_out scratch: hidden hi/lo splits (GEMM1), then xdbl/Aeff2/P/S/xpw splits.
// ---------------------------------------------------------------------------

#define BATCH   2
#define SEQLEN  4096
#define DMODEL  1024
#define DINNER  2048
#define E2      4096
#define DSTATE  8
#define DTRANK  64
#define NK      80
#define BL      (BATCH * SEQLEN)
#define CHUNK   64
#define NCHUNK  (SEQLEN / CHUNK)   // 64
#define LOG2E   1.44269504088896341f

typedef short bf16x8 __attribute__((ext_vector_type(8)));
typedef float f32x4  __attribute__((ext_vector_type(4)));
typedef unsigned short ushort8 __attribute__((ext_vector_type(8)));

__device__ __forceinline__ unsigned short f2bf(float f) {
    unsigned u = __float_as_uint(f);
    u += 0x7FFF + ((u >> 16) & 1);
    return (unsigned short)(u >> 16);
}
__device__ __forceinline__ float bf2f(unsigned short h) {
    return __uint_as_float((unsigned)h << 16);
}
// 2^x via the hardware transcendental (1-ulp; args here are well in range)
__device__ __forceinline__ float fexp2(float x) {
    float r;
    asm("v_exp_f32 %0, %1" : "=v"(r) : "v"(x));
    return r;
}
__device__ __forceinline__ float frcp(float x) {
    float r;
    asm("v_rcp_f32 %0, %1" : "=v"(r) : "v"(x));
    return r;
}

// ---------------------------------------------------------------------------
// Elementwise fp32 -> planar (hi, lo) bf16 split. n4 = n/4 float4 groups.
// ---------------------------------------------------------------------------
__global__ __launch_bounds__(256) void split_kernel(
    const float* __restrict__ src,
    unsigned short* __restrict__ hi, unsigned short* __restrict__ lo, int n4)
{
    int i = blockIdx.x * 256 + threadIdx.x;
    if (i >= n4) return;
    float4 v = ((const float4*)src)[i];
    ushort4 h, l;
    h.x = f2bf(v.x); h.y = f2bf(v.y); h.z = f2bf(v.z); h.w = f2bf(v.w);
    l.x = f2bf(v.x - bf2f(h.x)); l.y = f2bf(v.y - bf2f(h.y));
    l.z = f2bf(v.z - bf2f(h.z)); l.w = f2bf(v.w - bf2f(h.w));
    ((ushort4*)hi)[i] = h;
    ((ushort4*)lo)[i] = l;
}

// ---------------------------------------------------------------------------
// Planar split-bf16 3-pass MFMA NT GEMM. C = A * B^T, fp32 accumulate.
// APK=0: planar hi/lo A. APK=1: packed uint (hi<<16|lo) A.
// SPLITC=1: N-split C store. 128x128 tile, BK=32, 4 waves.
// LDS: unpadded [128][32] ushort rows + bijective XOR swizzle
//   o = row*32 + col;  o ^= (row&7)<<3   (ushort units; 16B-slot bits)
// -> fragment-read quad index bits {c3^r0, c4^r1, r0^r2}: 8 consecutive rows
//    hit 8 distinct quads -> 2-way max aliasing (free, m136).
// ---------------------------------------------------------------------------
#define LDSW 32

__device__ __forceinline__ int swz(int row, int col_u) {
    return ((row << 5) + col_u) ^ ((row & 7) << 3);
}

template <int APK, int SPLITC>
__global__ __launch_bounds__(256) void gemm_bf3p(
    const unsigned short* __restrict__ Ah_g,
    const unsigned short* __restrict__ Al_g, int lda,
    const unsigned short* __restrict__ Bh_g,
    const unsigned short* __restrict__ Bl_g, int ldb,
    float* __restrict__ C0, float* __restrict__ C1, int ldc,
    int N, int K)
{
    __shared__ unsigned short Ah[128 * LDSW], Al[128 * LDSW];
    __shared__ unsigned short Bh[128 * LDSW], Bl[128 * LDSW];

    const int tid  = threadIdx.x;
    const int lane = tid & 63;
    const int wave = tid >> 6;
    const int bm   = blockIdx.y << 7;
    const int bn   = blockIdx.x << 7;

    const int sr = tid >> 2;          // 0..63
    const int sc = (tid & 3) << 3;    // ushort col: 0,8,16,24

    const int pr = tid >> 3;          // 0..31
    const int pc = (tid & 7) << 2;    // ushort col: 0,4,...,28

    const int wm = (wave >> 1) << 6;
    const int wn = (wave & 1) << 6;
    const int fr = lane & 15;
    const int kg = lane >> 4;

    f32x4 acc[4][4];
#pragma unroll
    for (int i = 0; i < 4; ++i)
#pragma unroll
        for (int j = 0; j < 4; ++j)
            acc[i][j] = (f32x4){0.f, 0.f, 0.f, 0.f};

    const ushort8 zz = {0, 0, 0, 0, 0, 0, 0, 0};

    for (int k0 = 0; k0 < K; k0 += 32) {
        ushort8 a_h[2], a_l[2], b_h[2], b_l[2];
        ushort4 p_h[4], p_l[4];

        if (APK == 0) {
#pragma unroll
            for (int s = 0; s < 2; ++s) {
                size_t ao = (size_t)(bm + sr + s * 64) * lda + k0 + sc;
                a_h[s] = *(const ushort8*)&Ah_g[ao];
                a_l[s] = *(const ushort8*)&Al_g[ao];
            }
        } else {
            const unsigned* Apk = (const unsigned*)Ah_g;
#pragma unroll
            for (int s = 0; s < 4; ++s) {
                size_t ao = (size_t)(bm + pr + s * 32) * lda + k0 + pc;
                uint4 pk = *(const uint4*)&Apk[ao];
                p_h[s].x = (unsigned short)(pk.x >> 16);
                p_h[s].y = (unsigned short)(pk.y >> 16);
                p_h[s].z = (unsigned short)(pk.z >> 16);
                p_h[s].w = (unsigned short)(pk.w >> 16);
                p_l[s].x = (unsigned short)(pk.x & 0xffff);
                p_l[s].y = (unsigned short)(pk.y & 0xffff);
                p_l[s].z = (unsigned short)(pk.z & 0xffff);
                p_l[s].w = (unsigned short)(pk.w & 0xffff);
            }
        }
#pragma unroll
        for (int s = 0; s < 2; ++s) {
            int r = bn + sr + s * 64;
            if (r < N) {
                size_t bo = (size_t)r * ldb + k0 + sc;
                b_h[s] = *(const ushort8*)&Bh_g[bo];
                b_l[s] = *(const ushort8*)&Bl_g[bo];
            } else {
                b_h[s] = zz; b_l[s] = zz;
            }
        }

        __syncthreads();
        if (APK == 0) {
#pragma unroll
            for (int s = 0; s < 2; ++s) {
                const int o = swz(sr + s * 64, sc);
                *(ushort8*)&Ah[o] = a_h[s];
                *(ushort8*)&Al[o] = a_l[s];
            }
        } else {
#pragma unroll
            for (int s = 0; s < 4; ++s) {
                const int o = swz(pr + s * 32, pc);
                *(ushort4*)&Ah[o] = p_h[s];
                *(ushort4*)&Al[o] = p_l[s];
            }
        }
#pragma unroll
        for (int s = 0; s < 2; ++s) {
            const int o = swz(sr + s * 64, sc);
            *(ushort8*)&Bh[o] = b_h[s];
            *(ushort8*)&Bl[o] = b_l[s];
        }
        __syncthreads();

        bf16x8 fa_h[4], fa_l[4], fb_h[4], fb_l[4];
#pragma unroll
        for (int f = 0; f < 4; ++f) {
            const int ra = swz(wm + f * 16 + fr, kg << 3);
            const int rb = swz(wn + f * 16 + fr, kg << 3);
            fa_h[f] = *(const bf16x8*)&Ah[ra];
            fa_l[f] = *(const bf16x8*)&Al[ra];
            fb_h[f] = *(const bf16x8*)&Bh[rb];
            fb_l[f] = *(const bf16x8*)&Bl[rb];
        }

#pragma unroll
        for (int i = 0; i < 4; ++i)
#pragma unroll
            for (int j = 0; j < 4; ++j) {
                acc[i][j] = __builtin_amdgcn_mfma_f32_16x16x32_bf16(
                    fa_h[i], fb_h[j], acc[i][j], 0, 0, 0);
                acc[i][j] = __builtin_amdgcn_mfma_f32_16x16x32_bf16(
                    fa_l[i], fb_h[j], acc[i][j], 0, 0, 0);
                acc[i][j] = __builtin_amdgcn_mfma_f32_16x16x32_bf16(
                    fa_h[i], fb_l[j], acc[i][j], 0, 0, 0);
            }
    }

    const int erow = (lane >> 4) << 2;
    const int ecol = lane & 15;
    float* Cw = C0;
    int cb = bn;
    if (SPLITC && bn >= DINNER) { Cw = C1; cb = bn - DINNER; }
#pragma unroll
    for (int i = 0; i < 4; ++i) {
        const int row0 = bm + wm + i * 16 + erow;
#pragma unroll
        for (int j = 0; j < 4; ++j) {
            const int col = wn + j * 16 + ecol;
            if (bn + col < N) {
#pragma unroll
                for (int r = 0; r < 4; ++r)
                    Cw[(size_t)(row0 + r) * ldc + cb + col] = acc[i][j][r];
            }
        }
    }
}

// ---------------------------------------------------------------------------
// fp32 NT GEMM with softplus(acc + bias[n]) epilogue (delta GEMM, K=64).
// ---------------------------------------------------------------------------
__global__ __launch_bounds__(256) void gemm_nt_sp(
    const float* __restrict__ A, int lda,
    const float* __restrict__ B, int ldb,
    const float* __restrict__ bias,
    float* __restrict__ C, int ldc,
    int N, int K)
{
    __shared__ float As[16][64];
    __shared__ float Bs[16][64];

    const int tid  = threadIdx.x;
    const int tx   = tid & 15;
    const int ty   = tid >> 4;
    const int bm   = blockIdx.y << 6;
    const int bn   = blockIdx.x << 6;
    const int lrow = tid >> 2;
    const int lcol = (tid & 3) << 2;

    const float* Aptr = A + (size_t)(bm + lrow) * lda + lcol;
    const float* Bptr = B + (size_t)(bn + lrow) * ldb + lcol;
    const bool   bval = (bn + lrow) < N;

    float acc[4][4] = {};

    for (int k0 = 0; k0 < K; k0 += 16) {
        float4 av = *(const float4*)(Aptr + k0);
        float4 bv = make_float4(0.f, 0.f, 0.f, 0.f);
        if (bval) bv = *(const float4*)(Bptr + k0);

        __syncthreads();
        As[lcol + 0][lrow] = av.x;
        As[lcol + 1][lrow] = av.y;
        As[lcol + 2][lrow] = av.z;
        As[lcol + 3][lrow] = av.w;
        Bs[lcol + 0][lrow] = bv.x;
        Bs[lcol + 1][lrow] = bv.y;
        Bs[lcol + 2][lrow] = bv.z;
        Bs[lcol + 3][lrow] = bv.w;
        __syncthreads();

#pragma unroll
        for (int kk = 0; kk < 16; ++kk) {
            float4 a4 = *(const float4*)&As[kk][ty << 2];
            float4 b4 = *(const float4*)&Bs[kk][tx << 2];
            float ar[4] = {a4.x, a4.y, a4.z, a4.w};
            float br[4] = {b4.x, b4.y, b4.z, b4.w};
#pragma unroll
            for (int i = 0; i < 4; ++i)
#pragma unroll
                for (int j = 0; j < 4; ++j)
                    acc[i][j] = fmaf(ar[i], br[j], acc[i][j]);
        }
    }

    const int cm = bm + (ty << 2);
    const int cn = bn + (tx << 2);
#pragma unroll
    for (int i = 0; i < 4; ++i) {
#pragma unroll
        for (int j = 0; j < 4; ++j) {
            int nn = cn + j;
            if (nn < N) {
                float v = acc[i][j] + bias[nn];
                v = (v > 20.f) ? v : log1pf(expf(v));
                C[(size_t)(cm + i) * ldc + nn] = v;
            }
        }
    }
}

// ---------------------------------------------------------------------------
// A_eff2[d][n] = (-exp(A_log) + scale*(U@V)/sqrt(8)) * log2(e)
// ---------------------------------------------------------------------------
__global__ __launch_bounds__(256) void a_eff_kernel(
    const float* __restrict__ A_log, const float* __restrict__ U,
    const float* __restrict__ V, const float* __restrict__ scale_p,
    float* __restrict__ Aeff2)
{
    int d = blockIdx.x * 256 + threadIdx.x;
    if (d >= DINNER) return;
    const float s = (*scale_p) * 0.35355339059327378f;  // 1/sqrt(8)
    float ur[8];
#pragma unroll
    for (int r = 0; r < 8; ++r) ur[r] = U[d * 8 + r];
#pragma unroll
    for (int n = 0; n < DSTATE; ++n) {
        float acc = 0.f;
#pragma unroll
        for (int r = 0; r < 8; ++r) acc = fmaf(ur[r], V[r * 8 + n], acc);
        Aeff2[d * 8 + n] = (-expf(A_log[d * 8 + n]) + s * acc) * LOG2E;
    }
}

// ---------------------------------------------------------------------------
// Depthwise causal conv (D_CONV=4) + bias + SiLU; emits planar hi/lo bf16.
// ---------------------------------------------------------------------------
__global__ __launch_bounds__(256) void conv_silu_kernel(
    const float* __restrict__ xbuf, const float* __restrict__ cw,
    const float* __restrict__ cb,
    unsigned short* __restrict__ xth, unsigned short* __restrict__ xtl)
{
    const int d = blockIdx.x * 256 + threadIdx.x;
    const int l = blockIdx.y;
    const int b = blockIdx.z;

    float4 w = *(const float4*)&cw[d * 4];
    size_t idx = ((size_t)b * SEQLEN + l) * DINNER + d;

    float acc = cb[d];
    if (l >= 3) acc = fmaf(w.x, xbuf[idx - 3 * (size_t)DINNER], acc);
    if (l >= 2) acc = fmaf(w.y, xbuf[idx - 2 * (size_t)DINNER], acc);
    if (l >= 1) acc = fmaf(w.z, xbuf[idx - 1 * (size_t)DINNER], acc);
    acc = fmaf(w.w, xbuf[idx], acc);

    float sig = 1.f / (1.f + expf(-acc));
    float v = acc * sig;
    unsigned short h = f2bf(v);
    xth[idx] = h;
    xtl[idx] = f2bf(v - bf2f(h));
}

// ---------------------------------------------------------------------------
// Scan phase 1 (thread-per-d): per-chunk (P, S). 8 n-states in registers.
// grid = (DINNER/256, NCHUNK, BATCH), block = 256.
// ---------------------------------------------------------------------------
__global__ __launch_bounds__(256) void scan_phase1(
    const float* __restrict__ delta,       // xbuf, stride DINNER
    const unsigned short* __restrict__ uh,
    const unsigned short* __restrict__ ul,
    const float* __restrict__ xdbl,        // (B*L, 80)
    const float* __restrict__ Aeff2,       // (2048, 8), * log2e
    float* __restrict__ P, float* __restrict__ S)
{
    const int d = blockIdx.x * 256 + threadIdx.x;
    const int c = blockIdx.y;
    const int b = blockIdx.z;

    const float4 a0 = *(const float4*)&Aeff2[d * 8];
    const float4 a1 = *(const float4*)&Aeff2[d * 8 + 4];

    float4 s0 = make_float4(0.f, 0.f, 0.f, 0.f);
    float4 s1 = make_float4(0.f, 0.f, 0.f, 0.f);
    float sdl = 0.f;

    size_t rowD = ((size_t)b * SEQLEN + (size_t)c * CHUNK) * DINNER + d;
    size_t rowX = ((size_t)b * SEQLEN + (size_t)c * CHUNK) * NK + DTRANK;

    for (int t = 0; t < CHUNK; ++t) {
        float dl = delta[rowD];
        float ut = bf2f(uh[rowD]) + bf2f(ul[rowD]);
        float4 B0 = *(const float4*)&xdbl[rowX];
        float4 B1 = *(const float4*)&xdbl[rowX + 4];
        float dlut = dl * ut;

        s0.x = fmaf(s0.x, fexp2(dl * a0.x), dlut * B0.x);
        s0.y = fmaf(s0.y, fexp2(dl * a0.y), dlut * B0.y);
        s0.z = fmaf(s0.z, fexp2(dl * a0.z), dlut * B0.z);
        s0.w = fmaf(s0.w, fexp2(dl * a0.w), dlut * B0.w);
        s1.x = fmaf(s1.x, fexp2(dl * a1.x), dlut * B1.x);
        s1.y = fmaf(s1.y, fexp2(dl * a1.y), dlut * B1.y);
        s1.z = fmaf(s1.z, fexp2(dl * a1.z), dlut * B1.z);
        s1.w = fmaf(s1.w, fexp2(dl * a1.w), dlut * B1.w);

        sdl += dl;
        rowD += DINNER; rowX += NK;
    }

    size_t idx = (((size_t)b * NCHUNK + c) * DINNER + d) * 8;
    float4 p0 = make_float4(fexp2(sdl * a0.x), fexp2(sdl * a0.y),
                            fexp2(sdl * a0.z), fexp2(sdl * a0.w));
    float4 p1 = make_float4(fexp2(sdl * a1.x), fexp2(sdl * a1.y),
                            fexp2(sdl * a1.z), fexp2(sdl * a1.w));
    *(float4*)&P[idx]     = p0;
    *(float4*)&P[idx + 4] = p1;
    *(float4*)&S[idx]     = s0;
    *(float4*)&S[idx + 4] = s1;
}

// ---------------------------------------------------------------------------
// Scan combine: sequential over NCHUNK chunks per (b,d,n). P <- H0 in place.
// ---------------------------------------------------------------------------
__global__ __launch_bounds__(256) void scan_combine(
    float* __restrict__ P, const float* __restrict__ S)
{
    const int i = blockIdx.x * 256 + threadIdx.x;
    if (i >= BATCH * DINNER * DSTATE) return;
    const int b  = i / (DINNER * DSTATE);
    const int dn = i - b * (DINNER * DSTATE);

    float running = 0.f;
    for (int c = 0; c < NCHUNK; ++c) {
        size_t idx = (size_t)(b * NCHUNK + c) * (DINNER * DSTATE) + dn;
        float Pc = P[idx];
        float Sc = S[idx];
        P[idx] = running;
        running = fmaf(running, Pc, Sc);
    }
}

// ---------------------------------------------------------------------------
// Scan phase 2 (thread-per-d): recurrence from H0; y overwrites delta in
// place as PACKED split-bf16 (hi<<16 | lo) for the out_proj APK=1 path.
// ---------------------------------------------------------------------------
__global__ __launch_bounds__(256) void scan_phase2(
    float* __restrict__ deltay,            // xbuf: delta read / packed y write
    const unsigned short* __restrict__ uh,
    const unsigned short* __restrict__ ul,
    const float* __restrict__ xdbl,
    const float* __restrict__ zbuf,        // stride DINNER
    const float* __restrict__ Aeff2,
    const float* __restrict__ Dvec,
    const float* __restrict__ H0)
{
    const int d = blockIdx.x * 256 + threadIdx.x;
    const int c = blockIdx.y;
    const int b = blockIdx.z;

    const float4 a0 = *(const float4*)&Aeff2[d * 8];
    const float4 a1 = *(const float4*)&Aeff2[d * 8 + 4];
    const float  Dd = Dvec[d];

    size_t hidx = (((size_t)b * NCHUNK + c) * DINNER + d) * 8;
    float4 h0 = *(const float4*)&H0[hidx];
    float4 h1 = *(const float4*)&H0[hidx + 4];

    size_t rowD = ((size_t)b * SEQLEN + (size_t)c * CHUNK) * DINNER + d;
    size_t rowX = ((size_t)b * SEQLEN + (size_t)c * CHUNK) * NK + DTRANK;

    for (int t = 0; t < CHUNK; ++t) {
        float dl = deltay[rowD];
        float ut = bf2f(uh[rowD]) + bf2f(ul[rowD]);
        float zt = zbuf[rowD];
        float4 B0 = *(const float4*)&xdbl[rowX];
        float4 B1 = *(const float4*)&xdbl[rowX + 4];
        float4 C0 = *(const float4*)&xdbl[rowX + 8];
        float4 C1 = *(const float4*)&xdbl[rowX + 12];
        float dlut = dl * ut;

        h0.x = fmaf(h0.x, fexp2(dl * a0.x), dlut * B0.x);
        h0.y = fmaf(h0.y, fexp2(dl * a0.y), dlut * B0.y);
        h0.z = fmaf(h0.z, fexp2(dl * a0.z), dlut * B0.z);
        h0.w = fmaf(h0.w, fexp2(dl * a0.w), dlut * B0.w);
        h1.x = fmaf(h1.x, fexp2(dl * a1.x), dlut * B1.x);
        h1.y = fmaf(h1.y, fexp2(dl * a1.y), dlut * B1.y);
        h1.z = fmaf(h1.z, fexp2(dl * a1.z), dlut * B1.z);
        h1.w = fmaf(h1.w, fexp2(dl * a1.w), dlut * B1.w);

        float p = h0.x * C0.x;
        p = fmaf(h0.y, C0.y, p);
        p = fmaf(h0.z, C0.z, p);
        p = fmaf(h0.w, C0.w, p);
        p = fmaf(h1.x, C1.x, p);
        p = fmaf(h1.y, C1.y, p);
        p = fmaf(h1.z, C1.z, p);
        p = fmaf(h1.w, C1.w, p);

        float sig = frcp(1.f + fexp2(-zt * LOG2E));
        float yv = (p + ut * Dd) * (zt * sig);
        unsigned short yhi = f2bf(yv);
        unsigned short ylo = f2bf(yv - bf2f(yhi));
        ((unsigned*)deltay)[rowD] = ((unsigned)yhi << 16) | ylo;

        rowD += DINNER; rowX += NK;
    }
}

// ---------------------------------------------------------------------------
// Launch
// ---------------------------------------------------------------------------
extern "C" void kernel_launch(void* const* d_in, const int* in_sizes, int n_in,
                              void* d_out, int out_size, void* d_ws, size_t ws_size,
                              hipStream_t stream)
{
    const float* hidden     = (const float*)d_in[0];
    const float* in_proj_w  = (const float*)d_in[1];
    const float* conv_w     = (const float*)d_in[2];
    const float* conv_b     = (const float*)d_in[3];
    const float* x_proj_w   = (const float*)d_in[4];
    const float* dt_proj_w  = (const float*)d_in[5];
    const float* dt_proj_b  = (const float*)d_in[6];
    const float* A_log      = (const float*)d_in[7];
    const float* Dvec       = (const float*)d_in[8];
    const float* out_proj_w = (const float*)d_in[9];
    const float* U_param    = (const float*)d_in[10];
    const float* V_param    = (const float*)d_in[11];
    const float* scale_p    = (const float*)d_in[12];
    float* out = (float*)d_out;

    // ---- d_ws layout (192 MiB) ----
    float* xbuf = (float*)d_ws;                              // BL*2048 f32
    float* zbuf = xbuf + (size_t)BL * DINNER;                // BL*2048 f32
    unsigned short* xth = (unsigned short*)(zbuf + (size_t)BL * DINNER);
    unsigned short* xtl = xth + (size_t)BL * DINNER;

    // in_proj_w splits live in the xt region until the conv overwrites it
    unsigned short* ipwh = xth;
    unsigned short* ipwl = xth + (size_t)E2 * DMODEL;

    // ---- d_out scratch ----
    unsigned short* hidh = (unsigned short*)out;
    unsigned short* hidl = hidh + (size_t)BL * DMODEL;
    float* xdbl = out;                                        //   655,360 f
    float* Aeff = xdbl + (size_t)BL * NK;                     //    16,384 f
    float* Parr = Aeff + (size_t)DINNER * DSTATE;             // 2,097,152 f
    float* Sarr = Parr + (size_t)BATCH * NCHUNK * DINNER * DSTATE;
    unsigned short* xpwh = (unsigned short*)(Sarr + (size_t)BATCH * NCHUNK * DINNER * DSTATE);
    unsigned short* xpwl = xpwh + (size_t)NK * DINNER;

    // out_proj_w splits reuse zbuf once z is consumed (after phase2)
    unsigned short* opwh = (unsigned short*)zbuf;
    unsigned short* opwl = opwh + (size_t)DMODEL * DINNER;

    // 0) pre-splits needed by GEMM1
    split_kernel<<<dim3(BL * DMODEL / 1024), 256, 0, stream>>>(
        hidden, hidh, hidl, BL * DMODEL / 4);
    split_kernel<<<dim3(E2 * DMODEL / 1024), 256, 0, stream>>>(
        in_proj_w, ipwh, ipwl, E2 * DMODEL / 4);

    // 1) [xbuf|zbuf] = hidden @ in_proj_w^T   (8192 x 4096, K=1024) [MFMA]
    gemm_bf3p<0, 1><<<dim3(E2 / 128, BL / 128), 256, 0, stream>>>(
        hidh, hidl, DMODEL, ipwh, ipwl, DMODEL,
        xbuf, zbuf, DINNER, E2, DMODEL);

    // 2) A_eff2 + x_proj_w splits (d_out scratch now free)
    a_eff_kernel<<<dim3(DINNER / 256), 256, 0, stream>>>(
        A_log, U_param, V_param, scale_p, Aeff);
    split_kernel<<<dim3(NK * DINNER / 1024), 256, 0, stream>>>(
        x_proj_w, xpwh, xpwl, NK * DINNER / 4);

    // 3) depthwise conv + silu -> planar xt (overwrites in_proj_w splits)
    conv_silu_kernel<<<dim3(DINNER / 256, SEQLEN, BATCH), 256, 0, stream>>>(
        xbuf, conv_w, conv_b, xth, xtl);

    // 4) x_dbl = xt @ x_proj_w^T   (8192 x 80, K=2048) [MFMA]
    gemm_bf3p<0, 0><<<dim3(1, BL / 128), 256, 0, stream>>>(
        xth, xtl, DINNER, xpwh, xpwl, DINNER,
        xdbl, nullptr, NK, NK, DINNER);

    // 5) delta = softplus(dt_lr @ dt_proj_w^T + b) -> xbuf (fp32, K=64)
    gemm_nt_sp<<<dim3(DINNER / 64, BL / 64), 256, 0, stream>>>(
        xdbl, NK, dt_proj_w, DTRANK, dt_proj_b, xbuf, DINNER, DINNER, DTRANK);

    // 6) chunked selective scan (thread-per-d); phase2 packs y in place
    scan_phase1<<<dim3(DINNER / 256, NCHUNK, BATCH), 256, 0, stream>>>(
        xbuf, xth, xtl, xdbl, Aeff, Parr, Sarr);
    scan_combine<<<dim3((BATCH * DINNER * DSTATE + 255) / 256), 256, 0, stream>>>(
        Parr, Sarr);
    scan_phase2<<<dim3(DINNER / 256, NCHUNK, BATCH), 256, 0, stream>>>(
        xbuf, xth, xtl, xdbl, zbuf, Aeff, Dvec, Parr);

    // 7) out_proj_w splits into zbuf (z consumed), then final GEMM
    split_kernel<<<dim3(DMODEL * DINNER / 1024), 256, 0, stream>>>(
        out_proj_w, opwh, opwl, DMODEL * DINNER / 4);

    // 8) out = y @ out_proj_w^T   (8192 x 1024, K=2048) [MFMA, packed A]
    gemm_bf3p<1, 0><<<dim3(DMODEL / 128, BL / 128), 256, 0, stream>>>(
        (const unsigned short*)xbuf, nullptr, DINNER, opwh, opwl, DINNER,
        out, nullptr, DMODEL, DMODEL, DINNER);
}

// Round 10
// 710.068 us; speedup vs baseline: 7.2128x; 1.0123x over previous
//
#include <hip/hip_runtime.h>
#include <hip/hip_bf16.h>
#include <math.h>

// ---------------------------------------------------------------------------
// Mamba forward. Planar split-bf16 (3-pass) MFMA GEMMs. B (weight) operands
// are pre-shuffled to FRAGMENT-MAJOR layout and loaded direct from global
// (coalesced, no LDS); A operand staged via swizzled LDS. fp32 GEMM w/
// softplus epilogue for delta; chunked 3-phase thread-per-d selective scan.
// Shapes: B=2, L=4096, D_MODEL=1024, D_INNER=2048, E2=4096, D_STATE=8,
//         D_CONV=4, DT_RANK=64, NK=80, R_RANK=8.
//
// d_ws (192 MiB): xbuf (BL,2048) fp32  [x -> conv -> dead -> delta -> y(pk)]
//                 zbuf (BL,2048) fp32  [z; after phase2: out_proj_w frags]
//                 xth/xtl (BL,2048) ushort planes  [in_proj_w frags first,
//                                                   then u hi/lo from conv]
// d_out scratch: hidden hi/lo splits (GEMM1), then xdbl/Aeff2/P/S/xpw frags.
//
// Fragment-major weight layout (per plane): element (n,k) stored at
//   ((n>>4)*(K>>5) + (k>>5))*512 + ((n&15) + 16*((k>>3)&3))*8 + (k&7)
// so a wave's fb load is uniform_base + lane*16B (one dwordx4, coalesced).
// ---------------------------------------------------------------------------

#define BATCH   2
#define SEQLEN  4096
#define DMODEL  1024
#define DINNER  2048
#define E2      4096
#define DSTATE  8
#define DTRANK  64
#define NK      80
#define BL      (BATCH * SEQLEN)
#define CHUNK   64
#define NCHUNK  (SEQLEN / CHUNK)   // 64
#define LOG2E   1.44269504088896341f

typedef short bf16x8 __attribute__((ext_vector_type(8)));
typedef float f32x4  __attribute__((ext_vector_type(4)));
typedef unsigned short ushort8 __attribute__((ext_vector_type(8)));

__device__ __forceinline__ unsigned short f2bf(float f) {
    unsigned u = __float_as_uint(f);
    u += 0x7FFF + ((u >> 16) & 1);
    return (unsigned short)(u >> 16);
}
__device__ __forceinline__ float bf2f(unsigned short h) {
    return __uint_as_float((unsigned)h << 16);
}
__device__ __forceinline__ float fexp2(float x) {
    float r;
    asm("v_exp_f32 %0, %1" : "=v"(r) : "v"(x));
    return r;
}
__device__ __forceinline__ float frcp(float x) {
    float r;
    asm("v_rcp_f32 %0, %1" : "=v"(r) : "v"(x));
    return r;
}

// ---------------------------------------------------------------------------
// Elementwise fp32 -> planar (hi, lo) bf16 split (row-major, for A operands).
// ---------------------------------------------------------------------------
__global__ __launch_bounds__(256) void split_kernel(
    const float* __restrict__ src,
    unsigned short* __restrict__ hi, unsigned short* __restrict__ lo, int n4)
{
    int i = blockIdx.x * 256 + threadIdx.x;
    if (i >= n4) return;
    float4 v = ((const float4*)src)[i];
    ushort4 h, l;
    h.x = f2bf(v.x); h.y = f2bf(v.y); h.z = f2bf(v.z); h.w = f2bf(v.w);
    l.x = f2bf(v.x - bf2f(h.x)); l.y = f2bf(v.y - bf2f(h.y));
    l.z = f2bf(v.z - bf2f(h.z)); l.w = f2bf(v.w - bf2f(h.w));
    ((ushort4*)hi)[i] = h;
    ((ushort4*)lo)[i] = l;
}

// ---------------------------------------------------------------------------
// fp32 (N,K) row-major -> fragment-major planar hi/lo bf16 (for B operands).
// One thread per k-octet. nthreads = N*K/8.
// ---------------------------------------------------------------------------
__global__ __launch_bounds__(256) void split_frag_kernel(
    const float* __restrict__ src,
    unsigned short* __restrict__ hi, unsigned short* __restrict__ lo,
    int K, int nthreads)
{
    int t = blockIdx.x * 256 + threadIdx.x;
    if (t >= nthreads) return;
    const int ko = K >> 3;             // k-octets per row
    int n = t / ko;
    int k = (t - n * ko) << 3;

    const float4* s = (const float4*)(src + (size_t)n * K + k);
    float4 v0 = s[0], v1 = s[1];
    float vv[8] = {v0.x, v0.y, v0.z, v0.w, v1.x, v1.y, v1.z, v1.w};
    ushort8 h, l;
#pragma unroll
    for (int j = 0; j < 8; ++j) {
        unsigned short hb = f2bf(vv[j]);
        h[j] = hb;
        l[j] = f2bf(vv[j] - bf2f(hb));
    }
    const int lane = (n & 15) + (((k >> 3) & 3) << 4);
    size_t addr = (((size_t)(n >> 4) * (K >> 5) + (k >> 5)) << 9) + lane * 8;
    *(ushort8*)&hi[addr] = h;
    *(ushort8*)&lo[addr] = l;
}

// ---------------------------------------------------------------------------
// Planar split-bf16 3-pass MFMA NT GEMM. C = A * B^T, fp32 accumulate.
// APK=0: planar hi/lo A (row-major). APK=1: packed uint (hi<<16|lo) A.
// B: fragment-major planar hi/lo, loaded DIRECT from global (no LDS).
// SPLITC=1: N-split C store. 128x128 tile, BK=32, 4 waves.
// A LDS: [128][32] ushort + XOR swizzle (o ^= (row&7)<<3).
// ---------------------------------------------------------------------------
#define LDSW 32

__device__ __forceinline__ int swz(int row, int col_u) {
    return ((row << 5) + col_u) ^ ((row & 7) << 3);
}

template <int APK, int SPLITC>
__global__ __launch_bounds__(256) void gemm_bf3p(
    const unsigned short* __restrict__ Ah_g,
    const unsigned short* __restrict__ Al_g, int lda,
    const unsigned short* __restrict__ Bfh,
    const unsigned short* __restrict__ Bfl,
    float* __restrict__ C0, float* __restrict__ C1, int ldc,
    int N, int K)
{
    __shared__ unsigned short Ah[128 * LDSW], Al[128 * LDSW];

    const int tid  = threadIdx.x;
    const int lane = tid & 63;
    const int wave = tid >> 6;
    const int bm   = blockIdx.y << 7;
    const int bn   = blockIdx.x << 7;
    const int KT   = K >> 5;

    const int sr = tid >> 2;          // 0..63
    const int sc = (tid & 3) << 3;    // ushort col: 0,8,16,24

    const int pr = tid >> 3;          // 0..31
    const int pc = (tid & 7) << 2;    // ushort col: 0,4,...,28

    const int wm = (wave >> 1) << 6;
    const int wn = (wave & 1) << 6;
    const int fr = lane & 15;
    const int kg = lane >> 4;

    f32x4 acc[4][4];
#pragma unroll
    for (int i = 0; i < 4; ++i)
#pragma unroll
        for (int j = 0; j < 4; ++j)
            acc[i][j] = (f32x4){0.f, 0.f, 0.f, 0.f};

    const bf16x8 zb = {0, 0, 0, 0, 0, 0, 0, 0};
    const int nf0 = (bn + wn) >> 4;   // base fragment-tile index for this wave

    for (int k0 = 0; k0 < K; k0 += 32) {
        // ---- B fragments: direct coalesced global loads (frag-major) ----
        bf16x8 fb_h[4], fb_l[4];
#pragma unroll
        for (int f = 0; f < 4; ++f) {
            if (bn + wn + f * 16 < N) {
                size_t ad = (((size_t)(nf0 + f) * KT + (k0 >> 5)) << 9)
                          + (size_t)lane * 8;
                fb_h[f] = *(const bf16x8*)&Bfh[ad];
                fb_l[f] = *(const bf16x8*)&Bfl[ad];
            } else {
                fb_h[f] = zb; fb_l[f] = zb;
            }
        }

        // ---- A staging: global -> reg ----
        ushort8 a_h[2], a_l[2];
        ushort4 p_h[4], p_l[4];
        if (APK == 0) {
#pragma unroll
            for (int s = 0; s < 2; ++s) {
                size_t ao = (size_t)(bm + sr + s * 64) * lda + k0 + sc;
                a_h[s] = *(const ushort8*)&Ah_g[ao];
                a_l[s] = *(const ushort8*)&Al_g[ao];
            }
        } else {
            const unsigned* Apk = (const unsigned*)Ah_g;
#pragma unroll
            for (int s = 0; s < 4; ++s) {
                size_t ao = (size_t)(bm + pr + s * 32) * lda + k0 + pc;
                uint4 pk = *(const uint4*)&Apk[ao];
                p_h[s].x = (unsigned short)(pk.x >> 16);
                p_h[s].y = (unsigned short)(pk.y >> 16);
                p_h[s].z = (unsigned short)(pk.z >> 16);
                p_h[s].w = (unsigned short)(pk.w >> 16);
                p_l[s].x = (unsigned short)(pk.x & 0xffff);
                p_l[s].y = (unsigned short)(pk.y & 0xffff);
                p_l[s].z = (unsigned short)(pk.z & 0xffff);
                p_l[s].w = (unsigned short)(pk.w & 0xffff);
            }
        }

        __syncthreads();   // previous iteration's LDS reads complete
        if (APK == 0) {
#pragma unroll
            for (int s = 0; s < 2; ++s) {
                const int o = swz(sr + s * 64, sc);
                *(ushort8*)&Ah[o] = a_h[s];
                *(ushort8*)&Al[o] = a_l[s];
            }
        } else {
#pragma unroll
            for (int s = 0; s < 4; ++s) {
                const int o = swz(pr + s * 32, pc);
                *(ushort4*)&Ah[o] = p_h[s];
                *(ushort4*)&Al[o] = p_l[s];
            }
        }
        __syncthreads();

        // ---- A fragments from LDS ----
        bf16x8 fa_h[4], fa_l[4];
#pragma unroll
        for (int f = 0; f < 4; ++f) {
            const int ra = swz(wm + f * 16 + fr, kg << 3);
            fa_h[f] = *(const bf16x8*)&Ah[ra];
            fa_l[f] = *(const bf16x8*)&Al[ra];
        }

#pragma unroll
        for (int i = 0; i < 4; ++i)
#pragma unroll
            for (int j = 0; j < 4; ++j) {
                acc[i][j] = __builtin_amdgcn_mfma_f32_16x16x32_bf16(
                    fa_h[i], fb_h[j], acc[i][j], 0, 0, 0);
                acc[i][j] = __builtin_amdgcn_mfma_f32_16x16x32_bf16(
                    fa_l[i], fb_h[j], acc[i][j], 0, 0, 0);
                acc[i][j] = __builtin_amdgcn_mfma_f32_16x16x32_bf16(
                    fa_h[i], fb_l[j], acc[i][j], 0, 0, 0);
            }
    }

    const int erow = (lane >> 4) << 2;
    const int ecol = lane & 15;
    float* Cw = C0;
    int cb = bn;
    if (SPLITC && bn >= DINNER) { Cw = C1; cb = bn - DINNER; }
#pragma unroll
    for (int i = 0; i < 4; ++i) {
        const int row0 = bm + wm + i * 16 + erow;
#pragma unroll
        for (int j = 0; j < 4; ++j) {
            const int col = wn + j * 16 + ecol;
            if (bn + col < N) {
#pragma unroll
                for (int r = 0; r < 4; ++r)
                    Cw[(size_t)(row0 + r) * ldc + cb + col] = acc[i][j][r];
            }
        }
    }
}

// ---------------------------------------------------------------------------
// fp32 NT GEMM with softplus(acc + bias[n]) epilogue (delta GEMM, K=64).
// ---------------------------------------------------------------------------
__global__ __launch_bounds__(256) void gemm_nt_sp(
    const float* __restrict__ A, int lda,
    const float* __restrict__ B, int ldb,
    const float* __restrict__ bias,
    float* __restrict__ C, int ldc,
    int N, int K)
{
    __shared__ float As[16][64];
    __shared__ float Bs[16][64];

    const int tid  = threadIdx.x;
    const int tx   = tid & 15;
    const int ty   = tid >> 4;
    const int bm   = blockIdx.y << 6;
    const int bn   = blockIdx.x << 6;
    const int lrow = tid >> 2;
    const int lcol = (tid & 3) << 2;

    const float* Aptr = A + (size_t)(bm + lrow) * lda + lcol;
    const float* Bptr = B + (size_t)(bn + lrow) * ldb + lcol;
    const bool   bval = (bn + lrow) < N;

    float acc[4][4] = {};

    for (int k0 = 0; k0 < K; k0 += 16) {
        float4 av = *(const float4*)(Aptr + k0);
        float4 bv = make_float4(0.f, 0.f, 0.f, 0.f);
        if (bval) bv = *(const float4*)(Bptr + k0);

        __syncthreads();
        As[lcol + 0][lrow] = av.x;
        As[lcol + 1][lrow] = av.y;
        As[lcol + 2][lrow] = av.z;
        As[lcol + 3][lrow] = av.w;
        Bs[lcol + 0][lrow] = bv.x;
        Bs[lcol + 1][lrow] = bv.y;
        Bs[lcol + 2][lrow] = bv.z;
        Bs[lcol + 3][lrow] = bv.w;
        __syncthreads();

#pragma unroll
        for (int kk = 0; kk < 16; ++kk) {
            float4 a4 = *(const float4*)&As[kk][ty << 2];
            float4 b4 = *(const float4*)&Bs[kk][tx << 2];
            float ar[4] = {a4.x, a4.y, a4.z, a4.w};
            float br[4] = {b4.x, b4.y, b4.z, b4.w};
#pragma unroll
            for (int i = 0; i < 4; ++i)
#pragma unroll
                for (int j = 0; j < 4; ++j)
                    acc[i][j] = fmaf(ar[i], br[j], acc[i][j]);
        }
    }

    const int cm = bm + (ty << 2);
    const int cn = bn + (tx << 2);
#pragma unroll
    for (int i = 0; i < 4; ++i) {
#pragma unroll
        for (int j = 0; j < 4; ++j) {
            int nn = cn + j;
            if (nn < N) {
                float v = acc[i][j] + bias[nn];
                v = (v > 20.f) ? v : log1pf(expf(v));
                C[(size_t)(cm + i) * ldc + nn] = v;
            }
        }
    }
}

// ---------------------------------------------------------------------------
// A_eff2[d][n] = (-exp(A_log) + scale*(U@V)/sqrt(8)) * log2(e)
// ---------------------------------------------------------------------------
__global__ __launch_bounds__(256) void a_eff_kernel(
    const float* __restrict__ A_log, const float* __restrict__ U,
    const float* __restrict__ V, const float* __restrict__ scale_p,
    float* __restrict__ Aeff2)
{
    int d = blockIdx.x * 256 + threadIdx.x;
    if (d >= DINNER) return;
    const float s = (*scale_p) * 0.35355339059327378f;  // 1/sqrt(8)
    float ur[8];
#pragma unroll
    for (int r = 0; r < 8; ++r) ur[r] = U[d * 8 + r];
#pragma unroll
    for (int n = 0; n < DSTATE; ++n) {
        float acc = 0.f;
#pragma unroll
        for (int r = 0; r < 8; ++r) acc = fmaf(ur[r], V[r * 8 + n], acc);
        Aeff2[d * 8 + n] = (-expf(A_log[d * 8 + n]) + s * acc) * LOG2E;
    }
}

// ---------------------------------------------------------------------------
// Depthwise causal conv (D_CONV=4) + bias + SiLU; emits planar hi/lo bf16.
// ---------------------------------------------------------------------------
__global__ __launch_bounds__(256) void conv_silu_kernel(
    const float* __restrict__ xbuf, const float* __restrict__ cw,
    const float* __restrict__ cb,
    unsigned short* __restrict__ xth, unsigned short* __restrict__ xtl)
{
    const int d = blockIdx.x * 256 + threadIdx.x;
    const int l = blockIdx.y;
    const int b = blockIdx.z;

    float4 w = *(const float4*)&cw[d * 4];
    size_t idx = ((size_t)b * SEQLEN + l) * DINNER + d;

    float acc = cb[d];
    if (l >= 3) acc = fmaf(w.x, xbuf[idx - 3 * (size_t)DINNER], acc);
    if (l >= 2) acc = fmaf(w.y, xbuf[idx - 2 * (size_t)DINNER], acc);
    if (l >= 1) acc = fmaf(w.z, xbuf[idx - 1 * (size_t)DINNER], acc);
    acc = fmaf(w.w, xbuf[idx], acc);

    float sig = 1.f / (1.f + expf(-acc));
    float v = acc * sig;
    unsigned short h = f2bf(v);
    xth[idx] = h;
    xtl[idx] = f2bf(v - bf2f(h));
}

// ---------------------------------------------------------------------------
// Scan phase 1 (thread-per-d): per-chunk (P, S). 8 n-states in registers.
// ---------------------------------------------------------------------------
__global__ __launch_bounds__(256) void scan_phase1(
    const float* __restrict__ delta,
    const unsigned short* __restrict__ uh,
    const unsigned short* __restrict__ ul,
    const float* __restrict__ xdbl,
    const float* __restrict__ Aeff2,
    float* __restrict__ P, float* __restrict__ S)
{
    const int d = blockIdx.x * 256 + threadIdx.x;
    const int c = blockIdx.y;
    const int b = blockIdx.z;

    const float4 a0 = *(const float4*)&Aeff2[d * 8];
    const float4 a1 = *(const float4*)&Aeff2[d * 8 + 4];

    float4 s0 = make_float4(0.f, 0.f, 0.f, 0.f);
    float4 s1 = make_float4(0.f, 0.f, 0.f, 0.f);
    float sdl = 0.f;

    size_t rowD = ((size_t)b * SEQLEN + (size_t)c * CHUNK) * DINNER + d;
    size_t rowX = ((size_t)b * SEQLEN + (size_t)c * CHUNK) * NK + DTRANK;

    for (int t = 0; t < CHUNK; ++t) {
        float dl = delta[rowD];
        float ut = bf2f(uh[rowD]) + bf2f(ul[rowD]);
        float4 B0 = *(const float4*)&xdbl[rowX];
        float4 B1 = *(const float4*)&xdbl[rowX + 4];
        float dlut = dl * ut;

        s0.x = fmaf(s0.x, fexp2(dl * a0.x), dlut * B0.x);
        s0.y = fmaf(s0.y, fexp2(dl * a0.y), dlut * B0.y);
        s0.z = fmaf(s0.z, fexp2(dl * a0.z), dlut * B0.z);
        s0.w = fmaf(s0.w, fexp2(dl * a0.w), dlut * B0.w);
        s1.x = fmaf(s1.x, fexp2(dl * a1.x), dlut * B1.x);
        s1.y = fmaf(s1.y, fexp2(dl * a1.y), dlut * B1.y);
        s1.z = fmaf(s1.z, fexp2(dl * a1.z), dlut * B1.z);
        s1.w = fmaf(s1.w, fexp2(dl * a1.w), dlut * B1.w);

        sdl += dl;
        rowD += DINNER; rowX += NK;
    }

    size_t idx = (((size_t)b * NCHUNK + c) * DINNER + d) * 8;
    float4 p0 = make_float4(fexp2(sdl * a0.x), fexp2(sdl * a0.y),
                            fexp2(sdl * a0.z), fexp2(sdl * a0.w));
    float4 p1 = make_float4(fexp2(sdl * a1.x), fexp2(sdl * a1.y),
                            fexp2(sdl * a1.z), fexp2(sdl * a1.w));
    *(float4*)&P[idx]     = p0;
    *(float4*)&P[idx + 4] = p1;
    *(float4*)&S[idx]     = s0;
    *(float4*)&S[idx + 4] = s1;
}

// ---------------------------------------------------------------------------
// Scan combine: sequential over NCHUNK chunks per (b,d,n). P <- H0 in place.
// ---------------------------------------------------------------------------
__global__ __launch_bounds__(256) void scan_combine(
    float* __restrict__ P, const float* __restrict__ S)
{
    const int i = blockIdx.x * 256 + threadIdx.x;
    if (i >= BATCH * DINNER * DSTATE) return;
    const int b  = i / (DINNER * DSTATE);
    const int dn = i - b * (DINNER * DSTATE);

    float running = 0.f;
    for (int c = 0; c < NCHUNK; ++c) {
        size_t idx = (size_t)(b * NCHUNK + c) * (DINNER * DSTATE) + dn;
        float Pc = P[idx];
        float Sc = S[idx];
        P[idx] = running;
        running = fmaf(running, Pc, Sc);
    }
}

// ---------------------------------------------------------------------------
// Scan phase 2 (thread-per-d): recurrence from H0; y overwrites delta in
// place as PACKED split-bf16 (hi<<16 | lo) for the out_proj APK=1 path.
// ---------------------------------------------------------------------------
__global__ __launch_bounds__(256) void scan_phase2(
    float* __restrict__ deltay,
    const unsigned short* __restrict__ uh,
    const unsigned short* __restrict__ ul,
    const float* __restrict__ xdbl,
    const float* __restrict__ zbuf,
    const float* __restrict__ Aeff2,
    const float* __restrict__ Dvec,
    const float* __restrict__ H0)
{
    const int d = blockIdx.x * 256 + threadIdx.x;
    const int c = blockIdx.y;
    const int b = blockIdx.z;

    const float4 a0 = *(const float4*)&Aeff2[d * 8];
    const float4 a1 = *(const float4*)&Aeff2[d * 8 + 4];
    const float  Dd = Dvec[d];

    size_t hidx = (((size_t)b * NCHUNK + c) * DINNER + d) * 8;
    float4 h0 = *(const float4*)&H0[hidx];
    float4 h1 = *(const float4*)&H0[hidx + 4];

    size_t rowD = ((size_t)b * SEQLEN + (size_t)c * CHUNK) * DINNER + d;
    size_t rowX = ((size_t)b * SEQLEN + (size_t)c * CHUNK) * NK + DTRANK;

    for (int t = 0; t < CHUNK; ++t) {
        float dl = deltay[rowD];
        float ut = bf2f(uh[rowD]) + bf2f(ul[rowD]);
        float zt = zbuf[rowD];
        float4 B0 = *(const float4*)&xdbl[rowX];
        float4 B1 = *(const float4*)&xdbl[rowX + 4];
        float4 C0 = *(const float4*)&xdbl[rowX + 8];
        float4 C1 = *(const float4*)&xdbl[rowX + 12];
        float dlut = dl * ut;

        h0.x = fmaf(h0.x, fexp2(dl * a0.x), dlut * B0.x);
        h0.y = fmaf(h0.y, fexp2(dl * a0.y), dlut * B0.y);
        h0.z = fmaf(h0.z, fexp2(dl * a0.z), dlut * B0.z);
        h0.w = fmaf(h0.w, fexp2(dl * a0.w), dlut * B0.w);
        h1.x = fmaf(h1.x, fexp2(dl * a1.x), dlut * B1.x);
        h1.y = fmaf(h1.y, fexp2(dl * a1.y), dlut * B1.y);
        h1.z = fmaf(h1.z, fexp2(dl * a1.z), dlut * B1.z);
        h1.w = fmaf(h1.w, fexp2(dl * a1.w), dlut * B1.w);

        float p = h0.x * C0.x;
        p = fmaf(h0.y, C0.y, p);
        p = fmaf(h0.z, C0.z, p);
        p = fmaf(h0.w, C0.w, p);
        p = fmaf(h1.x, C1.x, p);
        p = fmaf(h1.y, C1.y, p);
        p = fmaf(h1.z, C1.z, p);
        p = fmaf(h1.w, C1.w, p);

        float sig = frcp(1.f + fexp2(-zt * LOG2E));
        float yv = (p + ut * Dd) * (zt * sig);
        unsigned short yhi = f2bf(yv);
        unsigned short ylo = f2bf(yv - bf2f(yhi));
        ((unsigned*)deltay)[rowD] = ((unsigned)yhi << 16) | ylo;

        rowD += DINNER; rowX += NK;
    }
}

// ---------------------------------------------------------------------------
// Launch
// ---------------------------------------------------------------------------
extern "C" void kernel_launch(void* const* d_in, const int* in_sizes, int n_in,
                              void* d_out, int out_size, void* d_ws, size_t ws_size,
                              hipStream_t stream)
{
    const float* hidden     = (const float*)d_in[0];
    const float* in_proj_w  = (const float*)d_in[1];
    const float* conv_w     = (const float*)d_in[2];
    const float* conv_b     = (const float*)d_in[3];
    const float* x_proj_w   = (const float*)d_in[4];
    const float* dt_proj_w  = (const float*)d_in[5];
    const float* dt_proj_b  = (const float*)d_in[6];
    const float* A_log      = (const float*)d_in[7];
    const float* Dvec       = (const float*)d_in[8];
    const float* out_proj_w = (const float*)d_in[9];
    const float* U_param    = (const float*)d_in[10];
    const float* V_param    = (const float*)d_in[11];
    const float* scale_p    = (const float*)d_in[12];
    float* out = (float*)d_out;

    // ---- d_ws layout (192 MiB) ----
    float* xbuf = (float*)d_ws;                              // BL*2048 f32
    float* zbuf = xbuf + (size_t)BL * DINNER;                // BL*2048 f32
    unsigned short* xth = (unsigned short*)(zbuf + (size_t)BL * DINNER);
    unsigned short* xtl = xth + (size_t)BL * DINNER;

    // in_proj_w fragment-major planes live in the xt region until conv
    unsigned short* ipwh = xth;
    unsigned short* ipwl = xth + (size_t)E2 * DMODEL;

    // ---- d_out scratch ----
    unsigned short* hidh = (unsigned short*)out;
    unsigned short* hidl = hidh + (size_t)BL * DMODEL;
    float* xdbl = out;                                        //   655,360 f
    float* Aeff = xdbl + (size_t)BL * NK;                     //    16,384 f
    float* Parr = Aeff + (size_t)DINNER * DSTATE;             // 2,097,152 f
    float* Sarr = Parr + (size_t)BATCH * NCHUNK * DINNER * DSTATE;
    unsigned short* xpwh = (unsigned short*)(Sarr + (size_t)BATCH * NCHUNK * DINNER * DSTATE);
    unsigned short* xpwl = xpwh + (size_t)NK * DINNER;

    // out_proj_w fragment-major planes reuse zbuf after phase2 consumes z
    unsigned short* opwh = (unsigned short*)zbuf;
    unsigned short* opwl = opwh + (size_t)DMODEL * DINNER;

    // 0) pre-splits needed by GEMM1 (A row-major planar; B fragment-major)
    split_kernel<<<dim3(BL * DMODEL / 1024), 256, 0, stream>>>(
        hidden, hidh, hidl, BL * DMODEL / 4);
    split_frag_kernel<<<dim3(E2 * DMODEL / 8 / 256), 256, 0, stream>>>(
        in_proj_w, ipwh, ipwl, DMODEL, E2 * DMODEL / 8);

    // 1) [xbuf|zbuf] = hidden @ in_proj_w^T   (8192 x 4096, K=1024) [MFMA]
    gemm_bf3p<0, 1><<<dim3(E2 / 128, BL / 128), 256, 0, stream>>>(
        hidh, hidl, DMODEL, ipwh, ipwl,
        xbuf, zbuf, DINNER, E2, DMODEL);

    // 2) A_eff2 + x_proj_w fragment-major split (d_out scratch now free)
    a_eff_kernel<<<dim3(DINNER / 256), 256, 0, stream>>>(
        A_log, U_param, V_param, scale_p, Aeff);
    split_frag_kernel<<<dim3(NK * DINNER / 8 / 256), 256, 0, stream>>>(
        x_proj_w, xpwh, xpwl, DINNER, NK * DINNER / 8);

    // 3) depthwise conv + silu -> planar xt (overwrites in_proj_w frags)
    conv_silu_kernel<<<dim3(DINNER / 256, SEQLEN, BATCH), 256, 0, stream>>>(
        xbuf, conv_w, conv_b, xth, xtl);

    // 4) x_dbl = xt @ x_proj_w^T   (8192 x 80, K=2048) [MFMA]
    gemm_bf3p<0, 0><<<dim3(1, BL / 128), 256, 0, stream>>>(
        xth, xtl, DINNER, xpwh, xpwl,
        xdbl, nullptr, NK, NK, DINNER);

    // 5) delta = softplus(dt_lr @ dt_proj_w^T + b) -> xbuf (fp32, K=64)
    gemm_nt_sp<<<dim3(DINNER / 64, BL / 64), 256, 0, stream>>>(
        xdbl, NK, dt_proj_w, DTRANK, dt_proj_b, xbuf, DINNER, DINNER, DTRANK);

    // 6) chunked selective scan (thread-per-d); phase2 packs y in place
    scan_phase1<<<dim3(DINNER / 256, NCHUNK, BATCH), 256, 0, stream>>>(
        xbuf, xth, xtl, xdbl, Aeff, Parr, Sarr);
    scan_combine<<<dim3((BATCH * DINNER * DSTATE + 255) / 256), 256, 0, stream>>>(
        Parr, Sarr);
    scan_phase2<<<dim3(DINNER / 256, NCHUNK, BATCH), 256, 0, stream>>>(
        xbuf, xth, xtl, xdbl, zbuf, Aeff, Dvec, Parr);

    // 7) out_proj_w fragment-major split into zbuf, then final GEMM
    split_frag_kernel<<<dim3(DMODEL * DINNER / 8 / 256), 256, 0, stream>>>(
        out_proj_w, opwh, opwl, DINNER, DMODEL * DINNER / 8);

    // 8) out = y @ out_proj_w^T   (8192 x 1024, K=2048) [MFMA, packed A]
    gemm_bf3p<1, 0><<<dim3(DMODEL / 128, BL / 128), 256, 0, stream>>>(
        (const unsigned short*)xbuf, nullptr, DINNER, opwh, opwl,
        out, nullptr, DMODEL, DMODEL, DINNER);
}